// Round 12
// baseline (5114.389 us; speedup 1.0000x reference)
//
#include <hip/hip_runtime.h>

typedef __bf16 bf16;
typedef __attribute__((ext_vector_type(8))) __bf16 bf16x8;
typedef __attribute__((ext_vector_type(4))) float f32x4;

#define GLOBAL_AS __attribute__((address_space(1)))
#define LDS_AS __attribute__((address_space(3)))

__device__ __forceinline__ void gload_lds16(const void* g, void* l) {
  __builtin_amdgcn_global_load_lds((const GLOBAL_AS void*)g, (LDS_AS void*)l, 16, 0, 0);
}
// cache-bypassing variant (sc0|sc1 = system scope): coherent-read-through
__device__ __forceinline__ void gload_lds16_cc(const void* g, void* l) {
  __builtin_amdgcn_global_load_lds((const GLOBAL_AS void*)g, (LDS_AS void*)l, 16, 0, 0x11);
}

__device__ __forceinline__ f32x4 mfma16(bf16x8 a, bf16x8 b, f32x4 c) {
  return __builtin_amdgcn_mfma_f32_16x16x32_bf16(a, b, c, 0, 0, 0);
}

// ---------------- constants ----------------
#define T_SEQ 300
#define NBATCH 32
#define DIN 320
#define NH 1024
#define NG 4096              // 4*NH
#define MROWS 9600           // T_SEQ*NBATCH
#define OUT_Y 19660800       // T*B*2H
#define HN_SZ 196608         // 6*32*1024

// ---------------- f32 -> bf16 convert ----------------
__global__ __launch_bounds__(256) void k_cvt(const float* __restrict__ src,
                                             bf16* __restrict__ dst, int n8) {
  int stride = gridDim.x * blockDim.x;
  for (int i = blockIdx.x * blockDim.x + threadIdx.x; i < n8; i += stride) {
    const float* s = src + (size_t)i * 8;
    f32x4 a = *(const f32x4*)s;
    f32x4 b = *(const f32x4*)(s + 4);
    bf16x8 o;
#pragma unroll
    for (int j = 0; j < 4; ++j) { o[j] = (bf16)a[j]; o[j + 4] = (bf16)b[j]; }
    *(bf16x8*)(dst + (size_t)i * 8) = o;
  }
}

// ---------------- bias sums: bsum[l][dir][4096] = b_ih + b_hh ----------------
__global__ __launch_bounds__(256) void k_bsum(const float* __restrict__ bih0,
                                              const float* __restrict__ bhh0,
                                              const float* __restrict__ bihL,
                                              const float* __restrict__ bhhL,
                                              float* __restrict__ bsum) {
  int i = blockIdx.x * 256 + threadIdx.x;  // n = 6*4096 = 24576
  if (i < 2 * NG) bsum[i] = bih0[i] + bhh0[i];
  else            bsum[i] = bihL[i - 2 * NG] + bhhL[i - 2 * NG];
}

// ---------------- GX GEMM (layer 0 only): gxT[dir][t][g][b][u] ----------------
__global__ __launch_bounds__(256) void k_gemm_gx(const bf16* __restrict__ A,
                                                 const bf16* __restrict__ Bw,
                                                 const float* __restrict__ bias,
                                                 bf16* __restrict__ gxout, int K) {
  __shared__ bf16 As[128 * 32];
  __shared__ bf16 Bs[128 * 32];
  const int t = threadIdx.x;
  const int m0 = blockIdx.y * 128, n0 = blockIdx.x * 128;
  const int lane = t & 63, wid = t >> 6;
  const int wr = wid >> 1, wc = wid & 1;
  const int fr = lane & 15, fq = lane >> 4;
  f32x4 acc[4][4] = {};
  for (int k0 = 0; k0 < K; k0 += 32) {
#pragma unroll
    for (int r = 0; r < 2; ++r) {
      int idx = r * 256 + t;
      int row = idx >> 2, kk = (idx & 3) * 8;
      gload_lds16(A + (size_t)(m0 + row) * K + k0 + kk, As + (size_t)idx * 8);
      gload_lds16(Bw + (size_t)(n0 + row) * K + k0 + kk, Bs + (size_t)idx * 8);
    }
    asm volatile("s_waitcnt vmcnt(0)" ::: "memory");
    __syncthreads();
    bf16x8 af[4], bf_[4];
#pragma unroll
    for (int i2 = 0; i2 < 4; ++i2) {
      af[i2]  = *(const bf16x8*)(As + (wr * 64 + i2 * 16 + fr) * 32 + fq * 8);
      bf_[i2] = *(const bf16x8*)(Bs + (wc * 64 + i2 * 16 + fr) * 32 + fq * 8);
    }
#pragma unroll
    for (int mi = 0; mi < 4; ++mi)
#pragma unroll
      for (int ni = 0; ni < 4; ++ni)
        acc[mi][ni] = mfma16(af[mi], bf_[ni], acc[mi][ni]);
    __syncthreads();
  }
#pragma unroll
  for (int ni = 0; ni < 4; ++ni) {
    int col = n0 + wc * 64 + ni * 16 + fr;
    float bv = bias[col];
    int dir = col >> 12, grow = col & (NG - 1);
    int gg = grow >> 10, uu = grow & 1023;
    bf16* base = gxout + ((size_t)dir * 300 * 4 + gg) * 32768 + uu;
#pragma unroll
    for (int mi = 0; mi < 4; ++mi) {
#pragma unroll
      for (int j = 0; j < 4; ++j) {
        int row = m0 + wr * 64 + mi * 16 + fq * 4 + j;
        int tt = row >> 5, b = row & 31;
        base[(size_t)tt * 131072 + b * 1024] = (bf16)(acc[mi][ni][j] + bv);
      }
    }
  }
}

// ---------------- per-layer init: h buffer (par 0) + flags ----------------
__global__ __launch_bounds__(256) void k_init(const float* __restrict__ h0,
                                              bf16* __restrict__ hbuf,
                                              int* __restrict__ flags, int layer) {
  int i = blockIdx.x * 256 + threadIdx.x;  // 65536 = [2 dir][32][1024]
  hbuf[i] = (bf16)h0[(size_t)layer * 65536 + i];
  if (blockIdx.x == 0 && threadIdx.x < 64) flags[threadIdx.x] = 0;
}

// ---------------- fused persistent kernel: recurrence + next-layer GEMM ----------------
// grid = 64 (+192 gemm) blocks x 512 threads; 84KB static LDS -> 1 block/CU -> all
// co-resident (grid <= 256 CUs): no dispatch-order deadlock. Blocks 0..63: r10 rec
// (proven 1244 us/layer). Blocks 64..255: 128x128 K=2048 GEMM tiles of the NEXT
// layer's gx, gated on step flags; flag-acquire fence + CACHED A reads (r12 change).
__global__ __launch_bounds__(512, 1) void k_rec(
    const bf16* __restrict__ whh,   // [2][4096][1024] (this layer)
    const bf16* __restrict__ gxT,   // [2][300][4][32][1024] bf16, biases folded
    const float* __restrict__ h0,   // [6][32][1024]
    bf16* __restrict__ hbuf,        // [2 par][2 dir][32][1024]
    int* __restrict__ flags,        // [64], zeroed by k_init
    bf16* __restrict__ yout,        // [9600][2048] or null (layer 2)
    float* __restrict__ dout,
    int layer,
    const bf16* __restrict__ gB,    // next-layer w_ih bf16 [8192][2048] (gemm role)
    const float* __restrict__ gbias,// next-layer bias sums [8192]
    int ngemm) {
  __shared__ char smem_[83968];
  // rec role:  [0..65536) h tile | EX f32 [4][128][33] aliases | [67584..83968) GXL 2x8KB
  // gemm role: [0..8192) As | [8192..16384) Bs
  float* EX = (float*)smem_;
  char* GXL = smem_ + 67584;

  const int tid = threadIdx.x;
  const int bid = blockIdx.x;

  // ================= GEMM role: blocks 64..63+ngemm =================
  if (bid >= 64) {
    const int gid = bid - 64;
    if (gid >= ngemm) return;
    bf16* As = (bf16*)smem_;
    bf16* Bs = (bf16*)(smem_ + 8192);
    const int lane = tid & 63, wid = tid >> 6;
    const int wr = wid >> 2, wc = wid & 3;     // 2x4 wave grid; wave tile 64x32
    const int fr = lane & 15, fq = lane >> 4;
    const int strow = tid >> 2, stkk = (tid & 3) * 8;   // staging: 512 thr x 16B = 8KB
#pragma unroll 1
    for (int i = 0; i < 25; ++i) {
      const int lin = i * 192 + gid;           // 4800 tiles = 75 m x 64 n
      const int n0 = (lin & 63) << 7;
      const int mrank = lin >> 6;              // readiness rank: center-out m
      const int m = (mrank & 1) ? (37 - ((mrank + 1) >> 1)) : (37 + (mrank >> 1));
      const int m0 = m << 7;
      const int ra = 4 * m + 3, rb = 299 - 4 * m;
      const int thr = (ra > rb ? ra : rb) + 2; // y(band) drained & gx(band) dead
      if (tid < 64) {
        while (__hip_atomic_load(&flags[tid], __ATOMIC_RELAXED,
                                 __HIP_MEMORY_SCOPE_AGENT) < thr)
          __builtin_amdgcn_s_sleep(32);
      }
      __syncthreads();
      // acquire: invalidate stale local L1/L2 so cached y reads see rec's stores
      __builtin_amdgcn_fence(__ATOMIC_ACQUIRE, "agent");
      f32x4 acc[4][2] = {};
      for (int k0 = 0; k0 < 2048; k0 += 32) {
        gload_lds16(yout + (size_t)(m0 + strow) * 2048 + k0 + stkk,
                    As + strow * 32 + stkk);
        gload_lds16(gB + (size_t)(n0 + strow) * 2048 + k0 + stkk,
                    Bs + strow * 32 + stkk);
        asm volatile("s_waitcnt vmcnt(0)" ::: "memory");
        __syncthreads();
        bf16x8 af[4], bfv[2];
#pragma unroll
        for (int i2 = 0; i2 < 4; ++i2)
          af[i2] = *(const bf16x8*)(As + (wr * 64 + i2 * 16 + fr) * 32 + fq * 8);
#pragma unroll
        for (int i2 = 0; i2 < 2; ++i2)
          bfv[i2] = *(const bf16x8*)(Bs + (wc * 32 + i2 * 16 + fr) * 32 + fq * 8);
#pragma unroll
        for (int mi = 0; mi < 4; ++mi)
#pragma unroll
          for (int ni = 0; ni < 2; ++ni)
            acc[mi][ni] = mfma16(af[mi], bfv[ni], acc[mi][ni]);
        __syncthreads();
      }
      // epilogue -> gxT layout (same as layer-0 GEMM)
#pragma unroll
      for (int ni = 0; ni < 2; ++ni) {
        int col = n0 + wc * 32 + ni * 16 + fr;
        float bv = gbias[col];
        int dirv = col >> 12, grow = col & (NG - 1);
        int gg = grow >> 10, uu = grow & 1023;
        bf16* base = (bf16*)gxT + ((size_t)dirv * 1200 + gg) * 32768 + uu;
#pragma unroll
        for (int mi = 0; mi < 4; ++mi) {
#pragma unroll
          for (int j = 0; j < 4; ++j) {
            int row = m0 + wr * 64 + mi * 16 + fq * 4 + j;
            int tt = row >> 5, b = row & 31;
            base[(size_t)tt * 131072 + b * 1024] = (bf16)(acc[mi][ni][j] + bv);
          }
        }
      }
    }
    return;
  }

  // ================= recurrence role: blocks 0..63 (r10, proven) =================
  const int dir = bid >> 5;
  const int rank = bid & 31;
  const int u0 = rank << 5;
  const int w = tid >> 6, lane = tid & 63;
  const int fr = lane & 15, fq = lane >> 4;
  const int kh = w >> 1, rh = w & 1;

  // ---- weights -> registers (64 rows x K=256 per wave = 128 regs/lane), pinned ----
  f32x4 wf[32];
#pragma unroll
  for (int rg = 0; rg < 4; ++rg) {
    int rowb = rh * 64 + rg * 16 + fr;  // block gate-row 0..127 (= g*32 + u_local)
    const bf16* Wp = whh + ((size_t)dir * 4096 + (rowb >> 5) * 1024 + u0 + (rowb & 31)) * 1024
                     + kh * 256 + fq * 8;
#pragma unroll
    for (int it = 0; it < 8; ++it) wf[rg * 8 + it] = *(const f32x4*)(Wp + it * 32);
  }
#pragma unroll
  for (int i = 0; i < 32; ++i) asm volatile("" : "+v"(wf[i]));

  // ---- cell state in registers; c init = h0 (reference's cn=hn bug) ----
  const int b_pt = tid >> 4;           // batch 0..31
  const int ul_pt = (tid & 15) << 1;   // local unit 0,2,..,30
  const int ug_pt = u0 + ul_pt;
  const size_t soff = ((size_t)layer * 2 + dir) * 32768 + (size_t)b_pt * 1024 + ug_pt;
  float c0 = h0[soff], c1 = h0[soff + 1];
  float hl0 = 0.f, hl1 = 0.f;

  // gx DMA mapping: thread -> (gate, b, 16B quarter)
  const int gg = tid >> 7, sub = tid & 127;
  const size_t gx_base0 = ((size_t)dir * 1200 + gg) * 32768
                          + (size_t)(sub >> 2) * 1024 + u0 + (sub & 3) * 8;

  // h-stage source offsets (t-invariant): linear LDS dest, inverse-swizzled source
  int srcoff[8];
#pragma unroll
  for (int r = 0; r < 8; ++r) {
    int d = r * 8192 + tid * 16;
    int row = d >> 11, colb = d & 2047;
    srcoff[r] = row * 2048 + (colb ^ ((row & 7) << 4));
  }
  const int swz = (fr & 7) << 4;

  // ---- prologue: gx(0) DMA into buffer 0 ----
  {
    const int ts0 = dir ? (T_SEQ - 1) : 0;
    gload_lds16(gxT + gx_base0 + (size_t)ts0 * 131072, GXL + tid * 16);
  }

#pragma unroll 1
  for (int t = 0; t < T_SEQ; ++t) {
    const int tseq = dir ? (T_SEQ - 1 - t) : t;

    // ---- barrier: all same-dir blocks published h(t-1) ----
    if (tid < 32) {
      while (__hip_atomic_load(&flags[dir * 32 + tid], __ATOMIC_RELAXED,
                               __HIP_MEMORY_SCOPE_AGENT) < t)
        __builtin_amdgcn_s_sleep(1);
    }
    __syncthreads();

    // ---- stage h(dir) 64KB -> LDS via coherence-point bypass loads ----
    const char* hsrc = (const char*)hbuf + (((size_t)(t & 1) * 2 + dir) << 16);
#pragma unroll
    for (int r = 0; r < 8; ++r)
      gload_lds16_cc(hsrc + srcoff[r], smem_ + r * 8192 + tid * 16);
    asm volatile("s_waitcnt vmcnt(0)" ::: "memory");
    __syncthreads();

    // ---- matvec: K-split-4, 64 MFMA from LDS(h) x reg(W) ----
    f32x4 acc[4][2] = {};
    const char* hb0 = smem_ + fr * 2048;
#pragma unroll
    for (int it = 0; it < 8; ++it) {
      int col = kh * 512 + it * 64 + fq * 16;
      bf16x8 ha0 = *(const bf16x8*)(hb0 + (col ^ swz));
      bf16x8 ha1 = *(const bf16x8*)(hb0 + 32768 + (col ^ swz));
#pragma unroll
      for (int rg = 0; rg < 4; ++rg) {
        bf16x8 wv = __builtin_bit_cast(bf16x8, wf[rg * 8 + it]);
        acc[rg][0] = mfma16(ha0, wv, acc[rg][0]);
        acc[rg][1] = mfma16(ha1, wv, acc[rg][1]);
      }
    }
    __syncthreads();  // all waves done reading h tile; EX aliases it

    // ---- exchange K-partials via LDS (f32, stride 33) ----
#pragma unroll
    for (int rg = 0; rg < 4; ++rg) {
      int rowb = rh * 64 + rg * 16 + fr;
      float* exr = EX + (size_t)(kh * 128 + rowb) * 33;
#pragma unroll
      for (int j = 0; j < 4; ++j) {
        exr[fq * 4 + j]      = acc[rg][0][j];
        exr[16 + fq * 4 + j] = acc[rg][1][j];
      }
    }
    __syncthreads();

    // ---- pointwise: 2 (b,u) pairs/thread; sum 4 K-partials + gx(LDS) ----
    const bf16* gxb = (const bf16*)(GXL + (t & 1) * 8192);
    float hv[2]; float cc[2] = {c0, c1};
#pragma unroll
    for (int q = 0; q < 2; ++q) {
      int ul = ul_pt + q;
      float gt[4];
#pragma unroll
      for (int g2 = 0; g2 < 4; ++g2) {
        int rowb = g2 * 32 + ul;
        float s = EX[(size_t)(0 * 128 + rowb) * 33 + b_pt]
                + EX[(size_t)(1 * 128 + rowb) * 33 + b_pt]
                + EX[(size_t)(2 * 128 + rowb) * 33 + b_pt]
                + EX[(size_t)(3 * 128 + rowb) * 33 + b_pt];
        gt[g2] = s + (float)gxb[(g2 * 32 + b_pt) * 32 + ul];
      }
      float iv = fminf(fmaxf(__builtin_fmaf(0.2f, gt[0], 0.5f), 0.f), 1.f);
      float fv = fminf(fmaxf(__builtin_fmaf(0.2f, gt[1], 0.5f), 0.f), 1.f);
      float gv = fminf(fmaxf(gt[2], -1.f), 1.f);
      float ov = fminf(fmaxf(__builtin_fmaf(0.2f, gt[3], 0.5f), 0.f), 1.f);
      float c = fv * cc[q] + iv * gv;
      cc[q] = c;
      hv[q] = ov * fminf(fmaxf(c, -1.f), 1.f);
    }
    c0 = cc[0]; c1 = cc[1]; hl0 = hv[0]; hl1 = hv[1];

    // ---- publish h (volatile write-through), drain, flag ----
    unsigned hp;
    { union { bf16 h[2]; unsigned u; } pk; pk.h[0] = (bf16)hv[0]; pk.h[1] = (bf16)hv[1]; hp = pk.u; }
    volatile unsigned* hdst =
        (volatile unsigned*)((char*)hbuf + (((size_t)((t + 1) & 1) * 2 + dir) << 16))
        + (((size_t)b_pt * 1024 + ug_pt) >> 1);
    *hdst = hp;
    asm volatile("s_waitcnt vmcnt(0)" ::: "memory");
    __syncthreads();   // all h stores at coherence point before flag release
    if (tid == 0)
      __hip_atomic_store(&flags[bid], t + 1, __ATOMIC_RELAXED, __HIP_MEMORY_SCOPE_AGENT);

    // ---- off-path: y stores (write-through: gemm consumers read via L3)
    //      + gx(t+1) prefetch; both drained by NEXT step's publish vmcnt ----
    if (yout) {
      volatile unsigned* yd =
          (volatile unsigned*)((char*)yout
              + (((size_t)tseq * 32 + b_pt) * 2048 + dir * 1024 + ug_pt) * 2);
      *yd = hp;
    } else {
      float* yd = dout + ((size_t)tseq * 32 + b_pt) * 2048 + dir * 1024 + ug_pt;
      yd[0] = hv[0]; yd[1] = hv[1];
    }
    if (t + 1 < T_SEQ) {
      const int tn = dir ? (T_SEQ - 2 - t) : (t + 1);
      gload_lds16(gxT + gx_base0 + (size_t)tn * 131072,
                  GXL + ((t + 1) & 1) * 8192 + tid * 16);
    }
  }

  // ---- final (h,c) states; drain everything; release terminal flag (>= all thr) ----
  dout[OUT_Y + soff] = hl0;
  dout[OUT_Y + soff + 1] = hl1;
  dout[OUT_Y + HN_SZ + soff] = c0;
  dout[OUT_Y + HN_SZ + soff + 1] = c1;
  asm volatile("s_waitcnt vmcnt(0)" ::: "memory");
  __syncthreads();
  if (tid == 0)
    __hip_atomic_store(&flags[bid], 302, __ATOMIC_RELAXED, __HIP_MEMORY_SCOPE_AGENT);
}

// ---------------- host launcher ----------------
extern "C" void kernel_launch(void* const* d_in, const int* in_sizes, int n_in,
                              void* d_out, int out_size, void* d_ws, size_t ws_size,
                              hipStream_t stream) {
  const float* x     = (const float*)d_in[0];
  const float* h0    = (const float*)d_in[1];
  // d_in[2] = c0: unused (reference init bug: cn = hn = h0)
  const float* w_ih0 = (const float*)d_in[3];
  const float* w_hh0 = (const float*)d_in[4];
  const float* b_ih0 = (const float*)d_in[5];
  const float* b_hh0 = (const float*)d_in[6];
  const float* w_ihL = (const float*)d_in[7];
  const float* w_hhL = (const float*)d_in[8];
  const float* b_ihL = (const float*)d_in[9];
  const float* b_hhL = (const float*)d_in[10];
  float* dout = (float*)d_out;
  char* ws = (char*)d_ws;

  // ---- workspace carve (bytes) ----
  const size_t OFF_XB   = 0;                         // bf16 [9600][320]
  const size_t OFF_WIH0 = 6144000;                   // bf16 [8192][320]
  const size_t OFF_WIHL = 11386880;                  // bf16 [2][8192][2048]
  const size_t OFF_WHH  = 78495744;                  // bf16 [6][4096][1024]
  const size_t OFF_BSUM = 128827392;                 // f32  [6][4096]
  const size_t OFF_GX   = 128925696;                 // bf16 [2][300][4][32][1024]
  const size_t OFF_Y0   = 286212096;                 // bf16 [9600][2048]
  const size_t OFF_Y1   = 325533696;                 // bf16 [9600][2048]
  const size_t OFF_HBF  = 364855296;                 // bf16 [2 par][2 dir][32][1024]
  const size_t OFF_FLG  = 365117440;                 // int  [64]

  bf16*  xb    = (bf16*)(ws + OFF_XB);
  bf16*  wih0b = (bf16*)(ws + OFF_WIH0);
  bf16*  wihLb = (bf16*)(ws + OFF_WIHL);
  bf16*  whhb  = (bf16*)(ws + OFF_WHH);
  float* bsum  = (float*)(ws + OFF_BSUM);
  bf16*  gx    = (bf16*)(ws + OFF_GX);
  bf16*  y0    = (bf16*)(ws + OFF_Y0);
  bf16*  y1    = (bf16*)(ws + OFF_Y1);
  bf16*  hbuf  = (bf16*)(ws + OFF_HBF);
  int*   flags = (int*)(ws + OFF_FLG);

  auto cvt = [&](const float* s, bf16* d, size_t n) {
    int n8 = (int)(n / 8);
    int grid = (n8 + 255) / 256; if (grid > 2048) grid = 2048;
    k_cvt<<<grid, 256, 0, stream>>>(s, d, n8);
  };

  cvt(x,     xb,    (size_t)MROWS * DIN);
  cvt(w_ih0, wih0b, (size_t)2 * NG * DIN);
  cvt(w_ihL, wihLb, (size_t)2 * 2 * NG * 2048);
  cvt(w_hh0, whhb,  (size_t)2 * NG * NH);
  cvt(w_hhL, whhb + (size_t)2 * NG * NH, (size_t)4 * NG * NH);
  k_bsum<<<96, 256, 0, stream>>>(b_ih0, b_hh0, b_ihL, b_hhL, bsum);

  // layer-0 gx GEMM (input x available immediately)
  k_gemm_gx<<<dim3(64, 75), 256, 0, stream>>>(xb, wih0b, bsum, gx, DIN);

  for (int l = 0; l < 3; ++l) {
    k_init<<<256, 256, 0, stream>>>(h0, hbuf, flags, l);

    const bf16* whh_l = whhb + (size_t)l * 2 * NG * NH;
    bf16* yout = (l == 0) ? y0 : (l == 1 ? y1 : nullptr);
    const int ngemm = (l < 2) ? 192 : 0;
    const bf16* gB = wihLb + (size_t)l * 2 * NG * 2048;   // next layer's w_ih
    const float* gbias = bsum + (size_t)(l + 1) * 2 * NG;
    k_rec<<<64 + ngemm, 512, 0, stream>>>(whh_l, gx, h0, hbuf, flags, yout, dout, l,
                                          gB, gbias, ngemm);
  }
  (void)in_sizes; (void)n_in; (void)out_size; (void)ws_size;
}

// Round 13
// 4752.514 us; speedup vs baseline: 1.0761x; 1.0761x over previous
//
#include <hip/hip_runtime.h>

typedef __bf16 bf16;
typedef __attribute__((ext_vector_type(8))) __bf16 bf16x8;
typedef __attribute__((ext_vector_type(4))) float f32x4;

#define GLOBAL_AS __attribute__((address_space(1)))
#define LDS_AS __attribute__((address_space(3)))

__device__ __forceinline__ void gload_lds16(const void* g, void* l) {
  __builtin_amdgcn_global_load_lds((const GLOBAL_AS void*)g, (LDS_AS void*)l, 16, 0, 0);
}
// cache-bypassing variant (sc0|sc1 = system scope): coherent-read-through
__device__ __forceinline__ void gload_lds16_cc(const void* g, void* l) {
  __builtin_amdgcn_global_load_lds((const GLOBAL_AS void*)g, (LDS_AS void*)l, 16, 0, 0x11);
}

__device__ __forceinline__ f32x4 mfma16(bf16x8 a, bf16x8 b, f32x4 c) {
  return __builtin_amdgcn_mfma_f32_16x16x32_bf16(a, b, c, 0, 0, 0);
}

// ---------------- constants ----------------
#define T_SEQ 300
#define NBATCH 32
#define DIN 320
#define NH 1024
#define NG 4096              // 4*NH
#define MROWS 9600           // T_SEQ*NBATCH
#define OUT_Y 19660800       // T*B*2H
#define HN_SZ 196608         // 6*32*1024

// ---------------- f32 -> bf16 convert ----------------
__global__ __launch_bounds__(256) void k_cvt(const float* __restrict__ src,
                                             bf16* __restrict__ dst, int n8) {
  int stride = gridDim.x * blockDim.x;
  for (int i = blockIdx.x * blockDim.x + threadIdx.x; i < n8; i += stride) {
    const float* s = src + (size_t)i * 8;
    f32x4 a = *(const f32x4*)s;
    f32x4 b = *(const f32x4*)(s + 4);
    bf16x8 o;
#pragma unroll
    for (int j = 0; j < 4; ++j) { o[j] = (bf16)a[j]; o[j + 4] = (bf16)b[j]; }
    *(bf16x8*)(dst + (size_t)i * 8) = o;
  }
}

// ---------------- bias sums: bsum[l][dir][4096] = b_ih + b_hh ----------------
__global__ __launch_bounds__(256) void k_bsum(const float* __restrict__ bih0,
                                              const float* __restrict__ bhh0,
                                              const float* __restrict__ bihL,
                                              const float* __restrict__ bhhL,
                                              float* __restrict__ bsum) {
  int i = blockIdx.x * 256 + threadIdx.x;  // n = 6*4096 = 24576
  if (i < 2 * NG) bsum[i] = bih0[i] + bhh0[i];
  else            bsum[i] = bihL[i - 2 * NG] + bhhL[i - 2 * NG];
}

// ---------------- GX GEMM (layer 0 only): gxT[dir][t][g][b][u] ----------------
__global__ __launch_bounds__(256) void k_gemm_gx(const bf16* __restrict__ A,
                                                 const bf16* __restrict__ Bw,
                                                 const float* __restrict__ bias,
                                                 bf16* __restrict__ gxout, int K) {
  __shared__ bf16 As[128 * 32];
  __shared__ bf16 Bs[128 * 32];
  const int t = threadIdx.x;
  const int m0 = blockIdx.y * 128, n0 = blockIdx.x * 128;
  const int lane = t & 63, wid = t >> 6;
  const int wr = wid >> 1, wc = wid & 1;
  const int fr = lane & 15, fq = lane >> 4;
  f32x4 acc[4][4] = {};
  for (int k0 = 0; k0 < K; k0 += 32) {
#pragma unroll
    for (int r = 0; r < 2; ++r) {
      int idx = r * 256 + t;
      int row = idx >> 2, kk = (idx & 3) * 8;
      gload_lds16(A + (size_t)(m0 + row) * K + k0 + kk, As + (size_t)idx * 8);
      gload_lds16(Bw + (size_t)(n0 + row) * K + k0 + kk, Bs + (size_t)idx * 8);
    }
    asm volatile("s_waitcnt vmcnt(0)" ::: "memory");
    __syncthreads();
    bf16x8 af[4], bf_[4];
#pragma unroll
    for (int i2 = 0; i2 < 4; ++i2) {
      af[i2]  = *(const bf16x8*)(As + (wr * 64 + i2 * 16 + fr) * 32 + fq * 8);
      bf_[i2] = *(const bf16x8*)(Bs + (wc * 64 + i2 * 16 + fr) * 32 + fq * 8);
    }
#pragma unroll
    for (int mi = 0; mi < 4; ++mi)
#pragma unroll
      for (int ni = 0; ni < 4; ++ni)
        acc[mi][ni] = mfma16(af[mi], bf_[ni], acc[mi][ni]);
    __syncthreads();
  }
#pragma unroll
  for (int ni = 0; ni < 4; ++ni) {
    int col = n0 + wc * 64 + ni * 16 + fr;
    float bv = bias[col];
    int dir = col >> 12, grow = col & (NG - 1);
    int gg = grow >> 10, uu = grow & 1023;
    bf16* base = gxout + ((size_t)dir * 300 * 4 + gg) * 32768 + uu;
#pragma unroll
    for (int mi = 0; mi < 4; ++mi) {
#pragma unroll
      for (int j = 0; j < 4; ++j) {
        int row = m0 + wr * 64 + mi * 16 + fq * 4 + j;
        int tt = row >> 5, b = row & 31;
        base[(size_t)tt * 131072 + b * 1024] = (bf16)(acc[mi][ni][j] + bv);
      }
    }
  }
}

// ---------------- per-layer init: h buffer (par 0) + flags ----------------
__global__ __launch_bounds__(256) void k_init(const float* __restrict__ h0,
                                              bf16* __restrict__ hbuf,
                                              int* __restrict__ flags, int layer) {
  int i = blockIdx.x * 256 + threadIdx.x;  // 65536 = [2 dir][32][1024]
  hbuf[i] = (bf16)h0[(size_t)layer * 65536 + i];
  if (blockIdx.x == 0 && threadIdx.x < 64) flags[threadIdx.x] = 0;
}

// ---------------- fused persistent kernel: recurrence + next-layer GEMM ----------------
// grid = 64 (+192 gemm) blocks x 512 threads; 96KB static LDS -> 1 block/CU -> all
// co-resident (grid <= 256 CUs). Blocks 0..63: r10 rec (proven 1244 us/layer).
// Blocks 64..255: 128x128 K=2048 GEMM tiles, flag-gated. r13 change: 6-deep
// counted-vmcnt staging pipeline (ILP replaces the TLP lost to 1-block/CU).
__global__ __launch_bounds__(512, 1) void k_rec(
    const bf16* __restrict__ whh,   // [2][4096][1024] (this layer)
    const bf16* __restrict__ gxT,   // [2][300][4][32][1024] bf16, biases folded
    const float* __restrict__ h0,   // [6][32][1024]
    bf16* __restrict__ hbuf,        // [2 par][2 dir][32][1024]
    int* __restrict__ flags,        // [64], zeroed by k_init
    bf16* __restrict__ yout,        // [9600][2048] or null (layer 2)
    float* __restrict__ dout,
    int layer,
    const bf16* __restrict__ gB,    // next-layer w_ih bf16 [8192][2048] (gemm role)
    const float* __restrict__ gbias,// next-layer bias sums [8192]
    int ngemm) {
  __shared__ char smem_[98304];
  // rec role:  [0..65536) h tile | EX f32 [4][128][33] aliases | [67584..83968) GXL 2x8KB
  // gemm role: 6-slot staging ring, slot s at [s*16384, s*16384+16384): As 8KB | Bs 8KB
  float* EX = (float*)smem_;
  char* GXL = smem_ + 67584;

  const int tid = threadIdx.x;
  const int bid = blockIdx.x;

  // ================= GEMM role: blocks 64..63+ngemm =================
  if (bid >= 64) {
    const int gid = bid - 64;
    if (gid >= ngemm) return;
    const int lane = tid & 63, wid = tid >> 6;
    const int wr = wid >> 2, wc = wid & 3;     // 2x4 wave grid; wave tile 64x32
    const int fr = lane & 15, fq = lane >> 4;
    const int strow = tid >> 2, stkk = (tid & 3) * 8;   // staging: 512 thr x 16B = 8KB each
#pragma unroll 1
    for (int i = 0; i < 25; ++i) {
      const int lin = i * 192 + gid;           // 4800 tiles = 75 m x 64 n
      const int n0 = (lin & 63) << 7;          // 192 % 64 == 0 -> n0 fixed per block
      const int mrank = lin >> 6;              // readiness rank: center-out m
      const int m = (mrank & 1) ? (37 - ((mrank + 1) >> 1)) : (37 + (mrank >> 1));
      const int m0 = m << 7;
      const int ra = 4 * m + 3, rb = 299 - 4 * m;
      const int thr = (ra > rb ? ra : rb) + 2; // y(band) drained & gx(band) dead
      if (tid < 64) {
        while (__hip_atomic_load(&flags[tid], __ATOMIC_RELAXED,
                                 __HIP_MEMORY_SCOPE_AGENT) < thr)
          __builtin_amdgcn_s_sleep(32);
      }
      __syncthreads();
      // acquire: invalidate stale local L1/L2 so cached y reads see rec's stores
      __builtin_amdgcn_fence(__ATOMIC_ACQUIRE, "agent");

      const bf16* Arow = yout + (size_t)(m0 + strow) * 2048 + stkk;
      const bf16* Brow = gB + (size_t)(n0 + strow) * 2048 + stkk;
      const int ldst = (strow * 32 + stkk) * 2;  // LDS byte offset within a slot

      auto stage = [&](int ks) {
        char* buf = smem_ + (ks % 6) * 16384;
        gload_lds16(Arow + ks * 32, buf + ldst);
        gload_lds16(Brow + ks * 32, buf + 8192 + ldst);
      };

      f32x4 acc[4][2] = {};
      auto compute = [&](int k) {
        const bf16* As = (const bf16*)(smem_ + (k % 6) * 16384);
        const bf16* Bs = As + 4096;
        bf16x8 af[4], bfv[2];
#pragma unroll
        for (int i2 = 0; i2 < 4; ++i2)
          af[i2] = *(const bf16x8*)(As + (wr * 64 + i2 * 16 + fr) * 32 + fq * 8);
#pragma unroll
        for (int i2 = 0; i2 < 2; ++i2)
          bfv[i2] = *(const bf16x8*)(Bs + (wc * 32 + i2 * 16 + fr) * 32 + fq * 8);
#pragma unroll
        for (int mi = 0; mi < 4; ++mi)
#pragma unroll
          for (int ni = 0; ni < 2; ++ni)
            acc[mi][ni] = mfma16(af[mi], bfv[ni], acc[mi][ni]);
      };

      // prologue: fill the 6-slot ring (12 outstanding loads/thread)
#pragma unroll
      for (int s = 0; s < 6; ++s) stage(s);

      // main: wait only for the oldest stage (2 loads) -> 10 may stay in flight
#pragma unroll 1
      for (int k = 0; k < 59; ++k) {
        asm volatile("s_waitcnt vmcnt(10)" ::: "memory");
        __builtin_amdgcn_s_barrier();
        compute(k);
        __builtin_amdgcn_sched_barrier(0);   // pin ds_read+MFMA before slot reuse
        __builtin_amdgcn_s_barrier();
        if (k + 6 < 64) stage(k + 6);
      }
      // tail: descending waits (outstanding shrinks; vmcnt(10) would pass vacuously)
#define GTAIL(K, WAITS)                                          \
      asm volatile("s_waitcnt vmcnt(" WAITS ")" ::: "memory");   \
      __builtin_amdgcn_s_barrier();                              \
      compute(K);                                                \
      __builtin_amdgcn_sched_barrier(0);                         \
      __builtin_amdgcn_s_barrier();
      GTAIL(59, "8") GTAIL(60, "6") GTAIL(61, "4") GTAIL(62, "2") GTAIL(63, "0")
#undef GTAIL

      // epilogue -> gxT layout (same as layer-0 GEMM)
#pragma unroll
      for (int ni = 0; ni < 2; ++ni) {
        int col = n0 + wc * 32 + ni * 16 + fr;
        float bv = gbias[col];
        int dirv = col >> 12, grow = col & (NG - 1);
        int gg = grow >> 10, uu = grow & 1023;
        bf16* base = (bf16*)gxT + ((size_t)dirv * 1200 + gg) * 32768 + uu;
#pragma unroll
        for (int mi = 0; mi < 4; ++mi) {
#pragma unroll
          for (int j = 0; j < 4; ++j) {
            int row = m0 + wr * 64 + mi * 16 + fq * 4 + j;
            int tt = row >> 5, b = row & 31;
            base[(size_t)tt * 131072 + b * 1024] = (bf16)(acc[mi][ni][j] + bv);
          }
        }
      }
    }
    return;
  }

  // ================= recurrence role: blocks 0..63 (r10, proven) =================
  const int dir = bid >> 5;
  const int rank = bid & 31;
  const int u0 = rank << 5;
  const int w = tid >> 6, lane = tid & 63;
  const int fr = lane & 15, fq = lane >> 4;
  const int kh = w >> 1, rh = w & 1;

  // ---- weights -> registers (64 rows x K=256 per wave = 128 regs/lane), pinned ----
  f32x4 wf[32];
#pragma unroll
  for (int rg = 0; rg < 4; ++rg) {
    int rowb = rh * 64 + rg * 16 + fr;  // block gate-row 0..127 (= g*32 + u_local)
    const bf16* Wp = whh + ((size_t)dir * 4096 + (rowb >> 5) * 1024 + u0 + (rowb & 31)) * 1024
                     + kh * 256 + fq * 8;
#pragma unroll
    for (int it = 0; it < 8; ++it) wf[rg * 8 + it] = *(const f32x4*)(Wp + it * 32);
  }
#pragma unroll
  for (int i = 0; i < 32; ++i) asm volatile("" : "+v"(wf[i]));

  // ---- cell state in registers; c init = h0 (reference's cn=hn bug) ----
  const int b_pt = tid >> 4;           // batch 0..31
  const int ul_pt = (tid & 15) << 1;   // local unit 0,2,..,30
  const int ug_pt = u0 + ul_pt;
  const size_t soff = ((size_t)layer * 2 + dir) * 32768 + (size_t)b_pt * 1024 + ug_pt;
  float c0 = h0[soff], c1 = h0[soff + 1];
  float hl0 = 0.f, hl1 = 0.f;

  // gx DMA mapping: thread -> (gate, b, 16B quarter)
  const int gg = tid >> 7, sub = tid & 127;
  const size_t gx_base0 = ((size_t)dir * 1200 + gg) * 32768
                          + (size_t)(sub >> 2) * 1024 + u0 + (sub & 3) * 8;

  // h-stage source offsets (t-invariant): linear LDS dest, inverse-swizzled source
  int srcoff[8];
#pragma unroll
  for (int r = 0; r < 8; ++r) {
    int d = r * 8192 + tid * 16;
    int row = d >> 11, colb = d & 2047;
    srcoff[r] = row * 2048 + (colb ^ ((row & 7) << 4));
  }
  const int swz = (fr & 7) << 4;

  // ---- prologue: gx(0) DMA into buffer 0 ----
  {
    const int ts0 = dir ? (T_SEQ - 1) : 0;
    gload_lds16(gxT + gx_base0 + (size_t)ts0 * 131072, GXL + tid * 16);
  }

#pragma unroll 1
  for (int t = 0; t < T_SEQ; ++t) {
    const int tseq = dir ? (T_SEQ - 1 - t) : t;

    // ---- barrier: all same-dir blocks published h(t-1) ----
    if (tid < 32) {
      while (__hip_atomic_load(&flags[dir * 32 + tid], __ATOMIC_RELAXED,
                               __HIP_MEMORY_SCOPE_AGENT) < t)
        __builtin_amdgcn_s_sleep(1);
    }
    __syncthreads();

    // ---- stage h(dir) 64KB -> LDS via coherence-point bypass loads ----
    const char* hsrc = (const char*)hbuf + (((size_t)(t & 1) * 2 + dir) << 16);
#pragma unroll
    for (int r = 0; r < 8; ++r)
      gload_lds16_cc(hsrc + srcoff[r], smem_ + r * 8192 + tid * 16);
    asm volatile("s_waitcnt vmcnt(0)" ::: "memory");
    __syncthreads();

    // ---- matvec: K-split-4, 64 MFMA from LDS(h) x reg(W) ----
    f32x4 acc[4][2] = {};
    const char* hb0 = smem_ + fr * 2048;
#pragma unroll
    for (int it = 0; it < 8; ++it) {
      int col = kh * 512 + it * 64 + fq * 16;
      bf16x8 ha0 = *(const bf16x8*)(hb0 + (col ^ swz));
      bf16x8 ha1 = *(const bf16x8*)(hb0 + 32768 + (col ^ swz));
#pragma unroll
      for (int rg = 0; rg < 4; ++rg) {
        bf16x8 wv = __builtin_bit_cast(bf16x8, wf[rg * 8 + it]);
        acc[rg][0] = mfma16(ha0, wv, acc[rg][0]);
        acc[rg][1] = mfma16(ha1, wv, acc[rg][1]);
      }
    }
    __syncthreads();  // all waves done reading h tile; EX aliases it

    // ---- exchange K-partials via LDS (f32, stride 33) ----
#pragma unroll
    for (int rg = 0; rg < 4; ++rg) {
      int rowb = rh * 64 + rg * 16 + fr;
      float* exr = EX + (size_t)(kh * 128 + rowb) * 33;
#pragma unroll
      for (int j = 0; j < 4; ++j) {
        exr[fq * 4 + j]      = acc[rg][0][j];
        exr[16 + fq * 4 + j] = acc[rg][1][j];
      }
    }
    __syncthreads();

    // ---- pointwise: 2 (b,u) pairs/thread; sum 4 K-partials + gx(LDS) ----
    const bf16* gxb = (const bf16*)(GXL + (t & 1) * 8192);
    float hv[2]; float cc[2] = {c0, c1};
#pragma unroll
    for (int q = 0; q < 2; ++q) {
      int ul = ul_pt + q;
      float gt[4];
#pragma unroll
      for (int g2 = 0; g2 < 4; ++g2) {
        int rowb = g2 * 32 + ul;
        float s = EX[(size_t)(0 * 128 + rowb) * 33 + b_pt]
                + EX[(size_t)(1 * 128 + rowb) * 33 + b_pt]
                + EX[(size_t)(2 * 128 + rowb) * 33 + b_pt]
                + EX[(size_t)(3 * 128 + rowb) * 33 + b_pt];
        gt[g2] = s + (float)gxb[(g2 * 32 + b_pt) * 32 + ul];
      }
      float iv = fminf(fmaxf(__builtin_fmaf(0.2f, gt[0], 0.5f), 0.f), 1.f);
      float fv = fminf(fmaxf(__builtin_fmaf(0.2f, gt[1], 0.5f), 0.f), 1.f);
      float gv = fminf(fmaxf(gt[2], -1.f), 1.f);
      float ov = fminf(fmaxf(__builtin_fmaf(0.2f, gt[3], 0.5f), 0.f), 1.f);
      float c = fv * cc[q] + iv * gv;
      cc[q] = c;
      hv[q] = ov * fminf(fmaxf(c, -1.f), 1.f);
    }
    c0 = cc[0]; c1 = cc[1]; hl0 = hv[0]; hl1 = hv[1];

    // ---- publish h (volatile write-through), drain, flag ----
    unsigned hp;
    { union { bf16 h[2]; unsigned u; } pk; pk.h[0] = (bf16)hv[0]; pk.h[1] = (bf16)hv[1]; hp = pk.u; }
    volatile unsigned* hdst =
        (volatile unsigned*)((char*)hbuf + (((size_t)((t + 1) & 1) * 2 + dir) << 16))
        + (((size_t)b_pt * 1024 + ug_pt) >> 1);
    *hdst = hp;
    asm volatile("s_waitcnt vmcnt(0)" ::: "memory");
    __syncthreads();   // all h stores at coherence point before flag release
    if (tid == 0)
      __hip_atomic_store(&flags[bid], t + 1, __ATOMIC_RELAXED, __HIP_MEMORY_SCOPE_AGENT);

    // ---- off-path: y stores (write-through: gemm consumers read via L3)
    //      + gx(t+1) prefetch; both drained by NEXT step's publish vmcnt ----
    if (yout) {
      volatile unsigned* yd =
          (volatile unsigned*)((char*)yout
              + (((size_t)tseq * 32 + b_pt) * 2048 + dir * 1024 + ug_pt) * 2);
      *yd = hp;
    } else {
      float* yd = dout + ((size_t)tseq * 32 + b_pt) * 2048 + dir * 1024 + ug_pt;
      yd[0] = hv[0]; yd[1] = hv[1];
    }
    if (t + 1 < T_SEQ) {
      const int tn = dir ? (T_SEQ - 2 - t) : (t + 1);
      gload_lds16(gxT + gx_base0 + (size_t)tn * 131072,
                  GXL + ((t + 1) & 1) * 8192 + tid * 16);
    }
  }

  // ---- final (h,c) states; drain everything; release terminal flag (>= all thr) ----
  dout[OUT_Y + soff] = hl0;
  dout[OUT_Y + soff + 1] = hl1;
  dout[OUT_Y + HN_SZ + soff] = c0;
  dout[OUT_Y + HN_SZ + soff + 1] = c1;
  asm volatile("s_waitcnt vmcnt(0)" ::: "memory");
  __syncthreads();
  if (tid == 0)
    __hip_atomic_store(&flags[bid], 302, __ATOMIC_RELAXED, __HIP_MEMORY_SCOPE_AGENT);
}

// ---------------- host launcher ----------------
extern "C" void kernel_launch(void* const* d_in, const int* in_sizes, int n_in,
                              void* d_out, int out_size, void* d_ws, size_t ws_size,
                              hipStream_t stream) {
  const float* x     = (const float*)d_in[0];
  const float* h0    = (const float*)d_in[1];
  // d_in[2] = c0: unused (reference init bug: cn = hn = h0)
  const float* w_ih0 = (const float*)d_in[3];
  const float* w_hh0 = (const float*)d_in[4];
  const float* b_ih0 = (const float*)d_in[5];
  const float* b_hh0 = (const float*)d_in[6];
  const float* w_ihL = (const float*)d_in[7];
  const float* w_hhL = (const float*)d_in[8];
  const float* b_ihL = (const float*)d_in[9];
  const float* b_hhL = (const float*)d_in[10];
  float* dout = (float*)d_out;
  char* ws = (char*)d_ws;

  // ---- workspace carve (bytes) ----
  const size_t OFF_XB   = 0;                         // bf16 [9600][320]
  const size_t OFF_WIH0 = 6144000;                   // bf16 [8192][320]
  const size_t OFF_WIHL = 11386880;                  // bf16 [2][8192][2048]
  const size_t OFF_WHH  = 78495744;                  // bf16 [6][4096][1024]
  const size_t OFF_BSUM = 128827392;                 // f32  [6][4096]
  const size_t OFF_GX   = 128925696;                 // bf16 [2][300][4][32][1024]
  const size_t OFF_Y0   = 286212096;                 // bf16 [9600][2048]
  const size_t OFF_Y1   = 325533696;                 // bf16 [9600][2048]
  const size_t OFF_HBF  = 364855296;                 // bf16 [2 par][2 dir][32][1024]
  const size_t OFF_FLG  = 365117440;                 // int  [64]

  bf16*  xb    = (bf16*)(ws + OFF_XB);
  bf16*  wih0b = (bf16*)(ws + OFF_WIH0);
  bf16*  wihLb = (bf16*)(ws + OFF_WIHL);
  bf16*  whhb  = (bf16*)(ws + OFF_WHH);
  float* bsum  = (float*)(ws + OFF_BSUM);
  bf16*  gx    = (bf16*)(ws + OFF_GX);
  bf16*  y0    = (bf16*)(ws + OFF_Y0);
  bf16*  y1    = (bf16*)(ws + OFF_Y1);
  bf16*  hbuf  = (bf16*)(ws + OFF_HBF);
  int*   flags = (int*)(ws + OFF_FLG);

  auto cvt = [&](const float* s, bf16* d, size_t n) {
    int n8 = (int)(n / 8);
    int grid = (n8 + 255) / 256; if (grid > 2048) grid = 2048;
    k_cvt<<<grid, 256, 0, stream>>>(s, d, n8);
  };

  cvt(x,     xb,    (size_t)MROWS * DIN);
  cvt(w_ih0, wih0b, (size_t)2 * NG * DIN);
  cvt(w_ihL, wihLb, (size_t)2 * 2 * NG * 2048);
  cvt(w_hh0, whhb,  (size_t)2 * NG * NH);
  cvt(w_hhL, whhb + (size_t)2 * NG * NH, (size_t)4 * NG * NH);
  k_bsum<<<96, 256, 0, stream>>>(b_ih0, b_hh0, b_ihL, b_hhL, bsum);

  // layer-0 gx GEMM (input x available immediately)
  k_gemm_gx<<<dim3(64, 75), 256, 0, stream>>>(xb, wih0b, bsum, gx, DIN);

  for (int l = 0; l < 3; ++l) {
    k_init<<<256, 256, 0, stream>>>(h0, hbuf, flags, l);

    const bf16* whh_l = whhb + (size_t)l * 2 * NG * NH;
    bf16* yout = (l == 0) ? y0 : (l == 1 ? y1 : nullptr);
    const int ngemm = (l < 2) ? 192 : 0;
    const bf16* gB = wihLb + (size_t)l * 2 * NG * 2048;   // next layer's w_ih
    const float* gbias = bsum + (size_t)(l + 1) * 2 * NG;
    k_rec<<<64 + ngemm, 512, 0, stream>>>(whh_l, gx, h0, hbuf, flags, yout, dout, l,
                                          gB, gbias, ngemm);
  }
  (void)in_sizes; (void)n_in; (void)out_size; (void)ws_size;
}

// Round 16
// 4713.941 us; speedup vs baseline: 1.0849x; 1.0082x over previous
//
#include <hip/hip_runtime.h>

typedef __bf16 bf16;
typedef __attribute__((ext_vector_type(8))) __bf16 bf16x8;
typedef __attribute__((ext_vector_type(4))) float f32x4;

#define GLOBAL_AS __attribute__((address_space(1)))
#define LDS_AS __attribute__((address_space(3)))

__device__ __forceinline__ void gload_lds16(const void* g, void* l) {
  __builtin_amdgcn_global_load_lds((const GLOBAL_AS void*)g, (LDS_AS void*)l, 16, 0, 0);
}
// cache-bypassing variant (sc0|sc1 = system scope): coherent-read-through
__device__ __forceinline__ void gload_lds16_cc(const void* g, void* l) {
  __builtin_amdgcn_global_load_lds((const GLOBAL_AS void*)g, (LDS_AS void*)l, 16, 0, 0x11);
}

__device__ __forceinline__ f32x4 mfma16(bf16x8 a, bf16x8 b, f32x4 c) {
  return __builtin_amdgcn_mfma_f32_16x16x32_bf16(a, b, c, 0, 0, 0);
}

// hardware barrier + compiler memory fence
#define GBAR() asm volatile("s_barrier" ::: "memory")

// ---------------- constants ----------------
#define T_SEQ 300
#define NBATCH 32
#define DIN 320
#define NH 1024
#define NG 4096              // 4*NH
#define MROWS 9600           // T_SEQ*NBATCH
#define OUT_Y 19660800       // T*B*2H
#define HN_SZ 196608         // 6*32*1024

// ---------------- f32 -> bf16 convert ----------------
__global__ __launch_bounds__(256) void k_cvt(const float* __restrict__ src,
                                             bf16* __restrict__ dst, int n8) {
  int stride = gridDim.x * blockDim.x;
  for (int i = blockIdx.x * blockDim.x + threadIdx.x; i < n8; i += stride) {
    const float* s = src + (size_t)i * 8;
    f32x4 a = *(const f32x4*)s;
    f32x4 b = *(const f32x4*)(s + 4);
    bf16x8 o;
#pragma unroll
    for (int j = 0; j < 4; ++j) { o[j] = (bf16)a[j]; o[j + 4] = (bf16)b[j]; }
    *(bf16x8*)(dst + (size_t)i * 8) = o;
  }
}

// ---------------- bias sums: bsum[l][dir][4096] = b_ih + b_hh ----------------
__global__ __launch_bounds__(256) void k_bsum(const float* __restrict__ bih0,
                                              const float* __restrict__ bhh0,
                                              const float* __restrict__ bihL,
                                              const float* __restrict__ bhhL,
                                              float* __restrict__ bsum) {
  int i = blockIdx.x * 256 + threadIdx.x;  // n = 6*4096 = 24576
  if (i < 2 * NG) bsum[i] = bih0[i] + bhh0[i];
  else            bsum[i] = bihL[i - 2 * NG] + bhhL[i - 2 * NG];
}

// ---------------- GX GEMM (layer 0 only): gxT[dir][t][g][b][u] ----------------
__global__ __launch_bounds__(256) void k_gemm_gx(const bf16* __restrict__ A,
                                                 const bf16* __restrict__ Bw,
                                                 const float* __restrict__ bias,
                                                 bf16* __restrict__ gxout, int K) {
  __shared__ bf16 As[128 * 32];
  __shared__ bf16 Bs[128 * 32];
  const int t = threadIdx.x;
  const int m0 = blockIdx.y * 128, n0 = blockIdx.x * 128;
  const int lane = t & 63, wid = t >> 6;
  const int wr = wid >> 1, wc = wid & 1;
  const int fr = lane & 15, fq = lane >> 4;
  f32x4 acc[4][4] = {};
  for (int k0 = 0; k0 < K; k0 += 32) {
#pragma unroll
    for (int r = 0; r < 2; ++r) {
      int idx = r * 256 + t;
      int row = idx >> 2, kk = (idx & 3) * 8;
      gload_lds16(A + (size_t)(m0 + row) * K + k0 + kk, As + (size_t)idx * 8);
      gload_lds16(Bw + (size_t)(n0 + row) * K + k0 + kk, Bs + (size_t)idx * 8);
    }
    asm volatile("s_waitcnt vmcnt(0)" ::: "memory");
    __syncthreads();
    bf16x8 af[4], bf_[4];
#pragma unroll
    for (int i2 = 0; i2 < 4; ++i2) {
      af[i2]  = *(const bf16x8*)(As + (wr * 64 + i2 * 16 + fr) * 32 + fq * 8);
      bf_[i2] = *(const bf16x8*)(Bs + (wc * 64 + i2 * 16 + fr) * 32 + fq * 8);
    }
#pragma unroll
    for (int mi = 0; mi < 4; ++mi)
#pragma unroll
      for (int ni = 0; ni < 4; ++ni)
        acc[mi][ni] = mfma16(af[mi], bf_[ni], acc[mi][ni]);
    __syncthreads();
  }
#pragma unroll
  for (int ni = 0; ni < 4; ++ni) {
    int col = n0 + wc * 64 + ni * 16 + fr;
    float bv = bias[col];
    int dir = col >> 12, grow = col & (NG - 1);
    int gg = grow >> 10, uu = grow & 1023;
    bf16* base = gxout + ((size_t)dir * 300 * 4 + gg) * 32768 + uu;
#pragma unroll
    for (int mi = 0; mi < 4; ++mi) {
#pragma unroll
      for (int j = 0; j < 4; ++j) {
        int row = m0 + wr * 64 + mi * 16 + fq * 4 + j;
        int tt = row >> 5, b = row & 31;
        base[(size_t)tt * 131072 + b * 1024] = (bf16)(acc[mi][ni][j] + bv);
      }
    }
  }
}

// ---------------- per-layer init: h buffer (par 0) + flags ----------------
__global__ __launch_bounds__(256) void k_init(const float* __restrict__ h0,
                                              bf16* __restrict__ hbuf,
                                              int* __restrict__ flags, int layer) {
  int i = blockIdx.x * 256 + threadIdx.x;  // 65536 = [2 dir][32][1024]
  hbuf[i] = (bf16)h0[(size_t)layer * 65536 + i];
  if (blockIdx.x == 0 && threadIdx.x < 64) flags[threadIdx.x] = 0;
}

// ---------------- fused persistent kernel: recurrence + next-layer GEMM ----------------
// grid = 64 (+192 gemm) blocks x 512 threads; 96KB static LDS -> 1 block/CU -> all
// co-resident (grid <= 256 CUs). Blocks 0..63: r10 rec (proven 1244 us/layer).
// Blocks 64..255: flag-gated 256x256 GEMM tiles (BK=32, 3-slot counted-vmcnt ring).
// r16 fix: global_load_lds writes LDS at wave-uniform-base + lane*16 (m104/m108) —
// every staging DMA now uses per-lane LDS addr == base + tid*16 (r14/r15 violated
// this with stride-32 per-thread addressing -> deterministic tile scramble).
__global__ __launch_bounds__(512, 1) void k_rec(
    const bf16* __restrict__ whh,   // [2][4096][1024] (this layer)
    const bf16* __restrict__ gxT,   // [2][300][4][32][1024] bf16, biases folded
    const float* __restrict__ h0,   // [6][32][1024]
    bf16* __restrict__ hbuf,        // [2 par][2 dir][32][1024]
    int* __restrict__ flags,        // [64], zeroed by k_init
    bf16* __restrict__ yout,        // [9600][2048] or null (layer 2)
    float* __restrict__ dout,
    int layer,
    const bf16* __restrict__ gB,    // next-layer w_ih bf16 [8192][2048] (gemm role)
    const float* __restrict__ gbias,// next-layer bias sums [8192]
    int ngemm) {
  __shared__ char smem_[98304];
  // rec role:  [0..65536) h tile | EX f32 [4][128][33] aliases | [67584..83968) GXL 2x8KB
  // gemm role: 3-slot ring, slot s at [s*32768): As 256x32 bf16 (16KB) | Bs 256x32 (16KB)
  float* EX = (float*)smem_;
  char* GXL = smem_ + 67584;

  const int tid = threadIdx.x;
  const int bid = blockIdx.x;

  // ================= GEMM role: blocks 64..63+ngemm =================
  if (bid >= 64) {
    const int gid = bid - 64;
    if (gid >= ngemm) return;
    const int lane = tid & 63, wid = tid >> 6;
    const int wm = wid >> 1, wn = wid & 1;     // 4m x 2n wave grid; wave tile 64x128
    const int fr = lane & 15, fq = lane >> 4;
    // staging: 512 threads sweep a [128][32] half-tile; LDS addr = base + tid*16
    const int srow = tid >> 2;                 // 0..127
    const int scol = (tid & 3) * 8;            // element col 0,8,16,24
    const int l16 = tid * 16;                  // lane-contiguous LDS byte offset
#pragma unroll 1
    for (int i = 0; i < 7; ++i) {
      const int lin = i * 192 + gid;           // 1216 tiles = 38 m x 32 n
      if (lin >= 1216) break;
      const int n0 = (lin & 31) << 8;          // fixed per block (192 % 32 == 0)
      const int mrank = lin >> 5;              // readiness rank: center-out m
      const int m = (mrank & 1) ? (19 + (mrank >> 1)) : (18 - (mrank >> 1));
      const int m0 = m << 8;
      int ra = 8 * m + 7; if (ra > 299) ra = 299;
      const int rb = 299 - 8 * m;
      const int thr = (ra > rb ? ra : rb) + 2; // y(band) drained & gx(band) dead
      if (tid < 64) {
        while (__hip_atomic_load(&flags[tid], __ATOMIC_RELAXED,
                                 __HIP_MEMORY_SCOPE_AGENT) < thr)
          __builtin_amdgcn_s_sleep(32);
      }
      __syncthreads();
      // acquire: invalidate stale local L1/L2 so cached y reads see rec's stores
      __builtin_amdgcn_fence(__ATOMIC_ACQUIRE, "agent");

      // band-37 A over-read past row 9599 lands in adjacent ws regions: safe
      const bf16* ArowL = yout + (size_t)(m0 + srow) * 2048 + scol;
      const bf16* ArowH = yout + (size_t)(m0 + 128 + srow) * 2048 + scol;
      const bf16* BrowL = gB + (size_t)(n0 + srow) * 2048 + scol;
      const bf16* BrowH = gB + (size_t)(n0 + 128 + srow) * 2048 + scol;

      auto stage = [&](int ks) {
        char* buf = smem_ + (ks % 3) * 32768;
        gload_lds16(ArowL + ks * 32, buf + l16);            // A rows   0..127
        gload_lds16(ArowH + ks * 32, buf + 8192 + l16);     // A rows 128..255
        gload_lds16(BrowL + ks * 32, buf + 16384 + l16);    // B rows   0..127
        gload_lds16(BrowH + ks * 32, buf + 24576 + l16);    // B rows 128..255
      };

      f32x4 acc[4][8] = {};
      auto compute = [&](int k) {
        const bf16* As = (const bf16*)(smem_ + (k % 3) * 32768);
        const bf16* Bs = As + 8192;
        bf16x8 af[4], bfv[8];
#pragma unroll
        for (int i2 = 0; i2 < 4; ++i2)
          af[i2] = *(const bf16x8*)(As + (wm * 64 + i2 * 16 + fr) * 32 + fq * 8);
#pragma unroll
        for (int i2 = 0; i2 < 8; ++i2)
          bfv[i2] = *(const bf16x8*)(Bs + (wn * 128 + i2 * 16 + fr) * 32 + fq * 8);
#pragma unroll
        for (int mi = 0; mi < 4; ++mi)
#pragma unroll
          for (int ni = 0; ni < 8; ++ni)
            acc[mi][ni] = mfma16(af[mi], bfv[ni], acc[mi][ni]);
      };

      // prologue: fill the 3-slot ring (12 outstanding loads/thread)
      stage(0); stage(1); stage(2);

      // main: wait only for the oldest stage (4 loads) -> 8 may stay in flight
#pragma unroll 1
      for (int k = 0; k < 61; ++k) {
        asm volatile("s_waitcnt vmcnt(8)" ::: "memory");
        GBAR();
        __builtin_amdgcn_sched_barrier(0);
        compute(k);
        __builtin_amdgcn_sched_barrier(0);
        GBAR();
        stage(k + 3);                        // k+3 <= 63
      }
      // tail: descending waits (no new stages; outstanding shrinks by 4 per iter)
#define GTAIL(K, WAITS)                                          \
      asm volatile("s_waitcnt vmcnt(" WAITS ")" ::: "memory");   \
      GBAR();                                                    \
      __builtin_amdgcn_sched_barrier(0);                         \
      compute(K);                                                \
      __builtin_amdgcn_sched_barrier(0);                         \
      GBAR();
      GTAIL(61, "8") GTAIL(62, "4") GTAIL(63, "0")
#undef GTAIL

      // epilogue -> gxT layout (same as layer-0 GEMM); guard row<9600 (band 37 half)
#pragma unroll
      for (int ni = 0; ni < 8; ++ni) {
        int col = n0 + wn * 128 + ni * 16 + fr;
        float bv = gbias[col];
        int dirv = col >> 12, grow = col & (NG - 1);
        int gg = grow >> 10, uu = grow & 1023;
        bf16* base = (bf16*)gxT + ((size_t)dirv * 1200 + gg) * 32768 + uu;
#pragma unroll
        for (int mi = 0; mi < 4; ++mi) {
#pragma unroll
          for (int j = 0; j < 4; ++j) {
            int row = m0 + wm * 64 + mi * 16 + fq * 4 + j;
            if (row < MROWS) {
              int tt = row >> 5, b = row & 31;
              base[(size_t)tt * 131072 + b * 1024] = (bf16)(acc[mi][ni][j] + bv);
            }
          }
        }
      }
    }
    return;
  }

  // ================= recurrence role: blocks 0..63 (r10, proven) =================
  const int dir = bid >> 5;
  const int rank = bid & 31;
  const int u0 = rank << 5;
  const int w = tid >> 6, lane = tid & 63;
  const int fr = lane & 15, fq = lane >> 4;
  const int kh = w >> 1, rh = w & 1;

  // ---- weights -> registers (64 rows x K=256 per wave = 128 regs/lane), pinned ----
  f32x4 wf[32];
#pragma unroll
  for (int rg = 0; rg < 4; ++rg) {
    int rowb = rh * 64 + rg * 16 + fr;  // block gate-row 0..127 (= g*32 + u_local)
    const bf16* Wp = whh + ((size_t)dir * 4096 + (rowb >> 5) * 1024 + u0 + (rowb & 31)) * 1024
                     + kh * 256 + fq * 8;
#pragma unroll
    for (int it = 0; it < 8; ++it) wf[rg * 8 + it] = *(const f32x4*)(Wp + it * 32);
  }
#pragma unroll
  for (int i = 0; i < 32; ++i) asm volatile("" : "+v"(wf[i]));

  // ---- cell state in registers; c init = h0 (reference's cn=hn bug) ----
  const int b_pt = tid >> 4;           // batch 0..31
  const int ul_pt = (tid & 15) << 1;   // local unit 0,2,..,30
  const int ug_pt = u0 + ul_pt;
  const size_t soff = ((size_t)layer * 2 + dir) * 32768 + (size_t)b_pt * 1024 + ug_pt;
  float c0 = h0[soff], c1 = h0[soff + 1];
  float hl0 = 0.f, hl1 = 0.f;

  // gx DMA mapping: thread -> (gate, b, 16B quarter)
  const int gg = tid >> 7, sub = tid & 127;
  const size_t gx_base0 = ((size_t)dir * 1200 + gg) * 32768
                          + (size_t)(sub >> 2) * 1024 + u0 + (sub & 3) * 8;

  // h-stage source offsets (t-invariant): linear LDS dest, inverse-swizzled source
  int srcoff[8];
#pragma unroll
  for (int r = 0; r < 8; ++r) {
    int d = r * 8192 + tid * 16;
    int row = d >> 11, colb = d & 2047;
    srcoff[r] = row * 2048 + (colb ^ ((row & 7) << 4));
  }
  const int swz = (fr & 7) << 4;

  // ---- prologue: gx(0) DMA into buffer 0 ----
  {
    const int ts0 = dir ? (T_SEQ - 1) : 0;
    gload_lds16(gxT + gx_base0 + (size_t)ts0 * 131072, GXL + tid * 16);
  }

#pragma unroll 1
  for (int t = 0; t < T_SEQ; ++t) {
    const int tseq = dir ? (T_SEQ - 1 - t) : t;

    // ---- barrier: all same-dir blocks published h(t-1) ----
    if (tid < 32) {
      while (__hip_atomic_load(&flags[dir * 32 + tid], __ATOMIC_RELAXED,
                               __HIP_MEMORY_SCOPE_AGENT) < t)
        __builtin_amdgcn_s_sleep(1);
    }
    __syncthreads();

    // ---- stage h(dir) 64KB -> LDS via coherence-point bypass loads ----
    const char* hsrc = (const char*)hbuf + (((size_t)(t & 1) * 2 + dir) << 16);
#pragma unroll
    for (int r = 0; r < 8; ++r)
      gload_lds16_cc(hsrc + srcoff[r], smem_ + r * 8192 + tid * 16);
    asm volatile("s_waitcnt vmcnt(0)" ::: "memory");
    __syncthreads();

    // ---- matvec: K-split-4, 64 MFMA from LDS(h) x reg(W) ----
    f32x4 acc[4][2] = {};
    const char* hb0 = smem_ + fr * 2048;
#pragma unroll
    for (int it = 0; it < 8; ++it) {
      int col = kh * 512 + it * 64 + fq * 16;
      bf16x8 ha0 = *(const bf16x8*)(hb0 + (col ^ swz));
      bf16x8 ha1 = *(const bf16x8*)(hb0 + 32768 + (col ^ swz));
#pragma unroll
      for (int rg = 0; rg < 4; ++rg) {
        bf16x8 wv = __builtin_bit_cast(bf16x8, wf[rg * 8 + it]);
        acc[rg][0] = mfma16(ha0, wv, acc[rg][0]);
        acc[rg][1] = mfma16(ha1, wv, acc[rg][1]);
      }
    }
    __syncthreads();  // all waves done reading h tile; EX aliases it

    // ---- exchange K-partials via LDS (f32, stride 33) ----
#pragma unroll
    for (int rg = 0; rg < 4; ++rg) {
      int rowb = rh * 64 + rg * 16 + fr;
      float* exr = EX + (size_t)(kh * 128 + rowb) * 33;
#pragma unroll
      for (int j = 0; j < 4; ++j) {
        exr[fq * 4 + j]      = acc[rg][0][j];
        exr[16 + fq * 4 + j] = acc[rg][1][j];
      }
    }
    __syncthreads();

    // ---- pointwise: 2 (b,u) pairs/thread; sum 4 K-partials + gx(LDS) ----
    const bf16* gxb = (const bf16*)(GXL + (t & 1) * 8192);
    float hv[2]; float cc[2] = {c0, c1};
#pragma unroll
    for (int q = 0; q < 2; ++q) {
      int ul = ul_pt + q;
      float gt[4];
#pragma unroll
      for (int g2 = 0; g2 < 4; ++g2) {
        int rowb = g2 * 32 + ul;
        float s = EX[(size_t)(0 * 128 + rowb) * 33 + b_pt]
                + EX[(size_t)(1 * 128 + rowb) * 33 + b_pt]
                + EX[(size_t)(2 * 128 + rowb) * 33 + b_pt]
                + EX[(size_t)(3 * 128 + rowb) * 33 + b_pt];
        gt[g2] = s + (float)gxb[(g2 * 32 + b_pt) * 32 + ul];
      }
      float iv = fminf(fmaxf(__builtin_fmaf(0.2f, gt[0], 0.5f), 0.f), 1.f);
      float fv = fminf(fmaxf(__builtin_fmaf(0.2f, gt[1], 0.5f), 0.f), 1.f);
      float gv = fminf(fmaxf(gt[2], -1.f), 1.f);
      float ov = fminf(fmaxf(__builtin_fmaf(0.2f, gt[3], 0.5f), 0.f), 1.f);
      float c = fv * cc[q] + iv * gv;
      cc[q] = c;
      hv[q] = ov * fminf(fmaxf(c, -1.f), 1.f);
    }
    c0 = cc[0]; c1 = cc[1]; hl0 = hv[0]; hl1 = hv[1];

    // ---- publish h (volatile write-through), drain, flag ----
    unsigned hp;
    { union { bf16 h[2]; unsigned u; } pk; pk.h[0] = (bf16)hv[0]; pk.h[1] = (bf16)hv[1]; hp = pk.u; }
    volatile unsigned* hdst =
        (volatile unsigned*)((char*)hbuf + (((size_t)((t + 1) & 1) * 2 + dir) << 16))
        + (((size_t)b_pt * 1024 + ug_pt) >> 1);
    *hdst = hp;
    asm volatile("s_waitcnt vmcnt(0)" ::: "memory");
    __syncthreads();   // all h stores at coherence point before flag release
    if (tid == 0)
      __hip_atomic_store(&flags[bid], t + 1, __ATOMIC_RELAXED, __HIP_MEMORY_SCOPE_AGENT);

    // ---- off-path: y stores (write-through: gemm consumers read via L3)
    //      + gx(t+1) prefetch; both drained by NEXT step's publish vmcnt ----
    if (yout) {
      volatile unsigned* yd =
          (volatile unsigned*)((char*)yout
              + (((size_t)tseq * 32 + b_pt) * 2048 + dir * 1024 + ug_pt) * 2);
      *yd = hp;
    } else {
      float* yd = dout + ((size_t)tseq * 32 + b_pt) * 2048 + dir * 1024 + ug_pt;
      yd[0] = hv[0]; yd[1] = hv[1];
    }
    if (t + 1 < T_SEQ) {
      const int tn = dir ? (T_SEQ - 2 - t) : (t + 1);
      gload_lds16(gxT + gx_base0 + (size_t)tn * 131072,
                  GXL + ((t + 1) & 1) * 8192 + tid * 16);
    }
  }

  // ---- final (h,c) states; drain everything; release terminal flag (>= all thr) ----
  dout[OUT_Y + soff] = hl0;
  dout[OUT_Y + soff + 1] = hl1;
  dout[OUT_Y + HN_SZ + soff] = c0;
  dout[OUT_Y + HN_SZ + soff + 1] = c1;
  asm volatile("s_waitcnt vmcnt(0)" ::: "memory");
  __syncthreads();
  if (tid == 0)
    __hip_atomic_store(&flags[bid], 302, __ATOMIC_RELAXED, __HIP_MEMORY_SCOPE_AGENT);
}

// ---------------- host launcher ----------------
extern "C" void kernel_launch(void* const* d_in, const int* in_sizes, int n_in,
                              void* d_out, int out_size, void* d_ws, size_t ws_size,
                              hipStream_t stream) {
  const float* x     = (const float*)d_in[0];
  const float* h0    = (const float*)d_in[1];
  // d_in[2] = c0: unused (reference init bug: cn = hn = h0)
  const float* w_ih0 = (const float*)d_in[3];
  const float* w_hh0 = (const float*)d_in[4];
  const float* b_ih0 = (const float*)d_in[5];
  const float* b_hh0 = (const float*)d_in[6];
  const float* w_ihL = (const float*)d_in[7];
  const float* w_hhL = (const float*)d_in[8];
  const float* b_ihL = (const float*)d_in[9];
  const float* b_hhL = (const float*)d_in[10];
  float* dout = (float*)d_out;
  char* ws = (char*)d_ws;

  // ---- workspace carve (bytes) ----
  const size_t OFF_XB   = 0;                         // bf16 [9600][320]
  const size_t OFF_WIH0 = 6144000;                   // bf16 [8192][320]
  const size_t OFF_WIHL = 11386880;                  // bf16 [2][8192][2048]
  const size_t OFF_WHH  = 78495744;                  // bf16 [6][4096][1024]
  const size_t OFF_BSUM = 128827392;                 // f32  [6][4096]
  const size_t OFF_GX   = 128925696;                 // bf16 [2][300][4][32][1024]
  const size_t OFF_Y0   = 286212096;                 // bf16 [9600][2048]
  const size_t OFF_Y1   = 325533696;                 // bf16 [9600][2048]
  const size_t OFF_HBF  = 364855296;                 // bf16 [2 par][2 dir][32][1024]
  const size_t OFF_FLG  = 365117440;                 // int  [64]

  bf16*  xb    = (bf16*)(ws + OFF_XB);
  bf16*  wih0b = (bf16*)(ws + OFF_WIH0);
  bf16*  wihLb = (bf16*)(ws + OFF_WIHL);
  bf16*  whhb  = (bf16*)(ws + OFF_WHH);
  float* bsum  = (float*)(ws + OFF_BSUM);
  bf16*  gx    = (bf16*)(ws + OFF_GX);
  bf16*  y0    = (bf16*)(ws + OFF_Y0);
  bf16*  y1    = (bf16*)(ws + OFF_Y1);
  bf16*  hbuf  = (bf16*)(ws + OFF_HBF);
  int*   flags = (int*)(ws + OFF_FLG);

  auto cvt = [&](const float* s, bf16* d, size_t n) {
    int n8 = (int)(n / 8);
    int grid = (n8 + 255) / 256; if (grid > 2048) grid = 2048;
    k_cvt<<<grid, 256, 0, stream>>>(s, d, n8);
  };

  cvt(x,     xb,    (size_t)MROWS * DIN);
  cvt(w_ih0, wih0b, (size_t)2 * NG * DIN);
  cvt(w_ihL, wihLb, (size_t)2 * 2 * NG * 2048);
  cvt(w_hh0, whhb,  (size_t)2 * NG * NH);
  cvt(w_hhL, whhb + (size_t)2 * NG * NH, (size_t)4 * NG * NH);
  k_bsum<<<96, 256, 0, stream>>>(b_ih0, b_hh0, b_ihL, b_hhL, bsum);

  // layer-0 gx GEMM (input x available immediately)
  k_gemm_gx<<<dim3(64, 75), 256, 0, stream>>>(xb, wih0b, bsum, gx, DIN);

  for (int l = 0; l < 3; ++l) {
    k_init<<<256, 256, 0, stream>>>(h0, hbuf, flags, l);

    const bf16* whh_l = whhb + (size_t)l * 2 * NG * NH;
    bf16* yout = (l == 0) ? y0 : (l == 1 ? y1 : nullptr);
    const int ngemm = (l < 2) ? 192 : 0;
    const bf16* gB = wihLb + (size_t)l * 2 * NG * 2048;   // next layer's w_ih
    const float* gbias = bsum + (size_t)(l + 1) * 2 * NG;
    k_rec<<<64 + ngemm, 512, 0, stream>>>(whh_l, gx, h0, hbuf, flags, yout, dout, l,
                                          gB, gbias, ngemm);
  }
  (void)in_sizes; (void)n_in; (void)out_size; (void)ws_size;
}

// Round 17
// 4705.676 us; speedup vs baseline: 1.0869x; 1.0018x over previous
//
#include <hip/hip_runtime.h>

typedef __bf16 bf16;
typedef __attribute__((ext_vector_type(8))) __bf16 bf16x8;
typedef __attribute__((ext_vector_type(4))) float f32x4;

#define GLOBAL_AS __attribute__((address_space(1)))
#define LDS_AS __attribute__((address_space(3)))

__device__ __forceinline__ void gload_lds16(const void* g, void* l) {
  __builtin_amdgcn_global_load_lds((const GLOBAL_AS void*)g, (LDS_AS void*)l, 16, 0, 0);
}
// cache-bypassing variant (sc0|sc1 = system scope): coherent-read-through
__device__ __forceinline__ void gload_lds16_cc(const void* g, void* l) {
  __builtin_amdgcn_global_load_lds((const GLOBAL_AS void*)g, (LDS_AS void*)l, 16, 0, 0x11);
}

__device__ __forceinline__ f32x4 mfma16(bf16x8 a, bf16x8 b, f32x4 c) {
  return __builtin_amdgcn_mfma_f32_16x16x32_bf16(a, b, c, 0, 0, 0);
}

// hardware barrier + compiler memory fence
#define GBAR() asm volatile("s_barrier" ::: "memory")

// ---------------- constants ----------------
#define T_SEQ 300
#define NBATCH 32
#define DIN 320
#define NH 1024
#define NG 4096              // 4*NH
#define MROWS 9600           // T_SEQ*NBATCH
#define OUT_Y 19660800       // T*B*2H
#define HN_SZ 196608         // 6*32*1024

// ---------------- f32 -> bf16 convert ----------------
__global__ __launch_bounds__(256) void k_cvt(const float* __restrict__ src,
                                             bf16* __restrict__ dst, int n8) {
  int stride = gridDim.x * blockDim.x;
  for (int i = blockIdx.x * blockDim.x + threadIdx.x; i < n8; i += stride) {
    const float* s = src + (size_t)i * 8;
    f32x4 a = *(const f32x4*)s;
    f32x4 b = *(const f32x4*)(s + 4);
    bf16x8 o;
#pragma unroll
    for (int j = 0; j < 4; ++j) { o[j] = (bf16)a[j]; o[j + 4] = (bf16)b[j]; }
    *(bf16x8*)(dst + (size_t)i * 8) = o;
  }
}

// ---------------- bias sums: bsum[l][dir][4096] = b_ih + b_hh ----------------
__global__ __launch_bounds__(256) void k_bsum(const float* __restrict__ bih0,
                                              const float* __restrict__ bhh0,
                                              const float* __restrict__ bihL,
                                              const float* __restrict__ bhhL,
                                              float* __restrict__ bsum) {
  int i = blockIdx.x * 256 + threadIdx.x;  // n = 6*4096 = 24576
  if (i < 2 * NG) bsum[i] = bih0[i] + bhh0[i];
  else            bsum[i] = bihL[i - 2 * NG] + bhhL[i - 2 * NG];
}

// ---------------- GX GEMM (layer 0 only): gxT[dir][t][g][b][u] ----------------
__global__ __launch_bounds__(256) void k_gemm_gx(const bf16* __restrict__ A,
                                                 const bf16* __restrict__ Bw,
                                                 const float* __restrict__ bias,
                                                 bf16* __restrict__ gxout, int K) {
  __shared__ bf16 As[128 * 32];
  __shared__ bf16 Bs[128 * 32];
  const int t = threadIdx.x;
  const int m0 = blockIdx.y * 128, n0 = blockIdx.x * 128;
  const int lane = t & 63, wid = t >> 6;
  const int wr = wid >> 1, wc = wid & 1;
  const int fr = lane & 15, fq = lane >> 4;
  f32x4 acc[4][4] = {};
  for (int k0 = 0; k0 < K; k0 += 32) {
#pragma unroll
    for (int r = 0; r < 2; ++r) {
      int idx = r * 256 + t;
      int row = idx >> 2, kk = (idx & 3) * 8;
      gload_lds16(A + (size_t)(m0 + row) * K + k0 + kk, As + (size_t)idx * 8);
      gload_lds16(Bw + (size_t)(n0 + row) * K + k0 + kk, Bs + (size_t)idx * 8);
    }
    asm volatile("s_waitcnt vmcnt(0)" ::: "memory");
    __syncthreads();
    bf16x8 af[4], bf_[4];
#pragma unroll
    for (int i2 = 0; i2 < 4; ++i2) {
      af[i2]  = *(const bf16x8*)(As + (wr * 64 + i2 * 16 + fr) * 32 + fq * 8);
      bf_[i2] = *(const bf16x8*)(Bs + (wc * 64 + i2 * 16 + fr) * 32 + fq * 8);
    }
#pragma unroll
    for (int mi = 0; mi < 4; ++mi)
#pragma unroll
      for (int ni = 0; ni < 4; ++ni)
        acc[mi][ni] = mfma16(af[mi], bf_[ni], acc[mi][ni]);
    __syncthreads();
  }
#pragma unroll
  for (int ni = 0; ni < 4; ++ni) {
    int col = n0 + wc * 64 + ni * 16 + fr;
    float bv = bias[col];
    int dir = col >> 12, grow = col & (NG - 1);
    int gg = grow >> 10, uu = grow & 1023;
    bf16* base = gxout + ((size_t)dir * 300 * 4 + gg) * 32768 + uu;
#pragma unroll
    for (int mi = 0; mi < 4; ++mi) {
#pragma unroll
      for (int j = 0; j < 4; ++j) {
        int row = m0 + wr * 64 + mi * 16 + fq * 4 + j;
        int tt = row >> 5, b = row & 31;
        base[(size_t)tt * 131072 + b * 1024] = (bf16)(acc[mi][ni][j] + bv);
      }
    }
  }
}

// ---------------- per-layer init: h buffer (par 0) + flags ----------------
__global__ __launch_bounds__(256) void k_init(const float* __restrict__ h0,
                                              bf16* __restrict__ hbuf,
                                              int* __restrict__ flags, int layer) {
  int i = blockIdx.x * 256 + threadIdx.x;  // 65536 = [2 dir][32][1024]
  hbuf[i] = (bf16)h0[(size_t)layer * 65536 + i];
  if (blockIdx.x == 0 && threadIdx.x < 64) flags[threadIdx.x] = 0;
}

// ---------------- fused persistent kernel: recurrence + next-layer GEMM ----------------
// grid = 64 (+192 gemm) blocks x 512 threads; 128KB static LDS -> 1 block/CU -> all
// co-resident (grid <= 256 CUs). Blocks 0..63: r10 rec (proven 1244 us/layer).
// Blocks 64..255: flag-gated 256x256 GEMM tiles (BK=32, counted-vmcnt ring).
// r17 change: ring 3->4 slots, wait vmcnt(8)->vmcnt(12): 96KB/block in flight
// matches the L3 latency x BW product (r16 was ~64KB -> 200-400ns stall per k-iter).
__global__ __launch_bounds__(512, 1) void k_rec(
    const bf16* __restrict__ whh,   // [2][4096][1024] (this layer)
    const bf16* __restrict__ gxT,   // [2][300][4][32][1024] bf16, biases folded
    const float* __restrict__ h0,   // [6][32][1024]
    bf16* __restrict__ hbuf,        // [2 par][2 dir][32][1024]
    int* __restrict__ flags,        // [64], zeroed by k_init
    bf16* __restrict__ yout,        // [9600][2048] or null (layer 2)
    float* __restrict__ dout,
    int layer,
    const bf16* __restrict__ gB,    // next-layer w_ih bf16 [8192][2048] (gemm role)
    const float* __restrict__ gbias,// next-layer bias sums [8192]
    int ngemm) {
  __shared__ char smem_[131072];
  // rec role:  [0..65536) h tile | EX f32 [4][128][33] aliases | [67584..83968) GXL 2x8KB
  // gemm role: 4-slot ring, slot s at [s*32768): As 256x32 bf16 (16KB) | Bs 256x32 (16KB)
  float* EX = (float*)smem_;
  char* GXL = smem_ + 67584;

  const int tid = threadIdx.x;
  const int bid = blockIdx.x;

  // ================= GEMM role: blocks 64..63+ngemm =================
  if (bid >= 64) {
    const int gid = bid - 64;
    if (gid >= ngemm) return;
    const int lane = tid & 63, wid = tid >> 6;
    const int wm = wid >> 1, wn = wid & 1;     // 4m x 2n wave grid; wave tile 64x128
    const int fr = lane & 15, fq = lane >> 4;
    // staging: 512 threads sweep a [128][32] half-tile; LDS addr = base + tid*16
    // (global_load_lds HW writes wave-uniform-base + lane*16 — must match, m104/m108)
    const int srow = tid >> 2;                 // 0..127
    const int scol = (tid & 3) * 8;            // element col 0,8,16,24
    const int l16 = tid * 16;                  // lane-contiguous LDS byte offset
#pragma unroll 1
    for (int i = 0; i < 7; ++i) {
      const int lin = i * 192 + gid;           // 1216 tiles = 38 m x 32 n
      if (lin >= 1216) break;
      const int n0 = (lin & 31) << 8;          // fixed per block (192 % 32 == 0)
      const int mrank = lin >> 5;              // readiness rank: center-out m
      const int m = (mrank & 1) ? (19 + (mrank >> 1)) : (18 - (mrank >> 1));
      const int m0 = m << 8;
      int ra = 8 * m + 7; if (ra > 299) ra = 299;
      const int rb = 299 - 8 * m;
      const int thr = (ra > rb ? ra : rb) + 2; // y(band) drained & gx(band) dead
      if (tid < 64) {
        while (__hip_atomic_load(&flags[tid], __ATOMIC_RELAXED,
                                 __HIP_MEMORY_SCOPE_AGENT) < thr)
          __builtin_amdgcn_s_sleep(32);
      }
      __syncthreads();
      // acquire: invalidate stale local L1/L2 so cached y reads see rec's stores
      __builtin_amdgcn_fence(__ATOMIC_ACQUIRE, "agent");

      // band-37 A over-read past row 9599 lands in adjacent ws regions: safe
      const bf16* ArowL = yout + (size_t)(m0 + srow) * 2048 + scol;
      const bf16* ArowH = yout + (size_t)(m0 + 128 + srow) * 2048 + scol;
      const bf16* BrowL = gB + (size_t)(n0 + srow) * 2048 + scol;
      const bf16* BrowH = gB + (size_t)(n0 + 128 + srow) * 2048 + scol;

      auto stage = [&](int ks) {
        char* buf = smem_ + (ks & 3) * 32768;
        gload_lds16(ArowL + ks * 32, buf + l16);            // A rows   0..127
        gload_lds16(ArowH + ks * 32, buf + 8192 + l16);     // A rows 128..255
        gload_lds16(BrowL + ks * 32, buf + 16384 + l16);    // B rows   0..127
        gload_lds16(BrowH + ks * 32, buf + 24576 + l16);    // B rows 128..255
      };

      f32x4 acc[4][8] = {};
      auto compute = [&](int k) {
        const bf16* As = (const bf16*)(smem_ + (k & 3) * 32768);
        const bf16* Bs = As + 8192;
        bf16x8 af[4], bfv[8];
#pragma unroll
        for (int i2 = 0; i2 < 4; ++i2)
          af[i2] = *(const bf16x8*)(As + (wm * 64 + i2 * 16 + fr) * 32 + fq * 8);
#pragma unroll
        for (int i2 = 0; i2 < 8; ++i2)
          bfv[i2] = *(const bf16x8*)(Bs + (wn * 128 + i2 * 16 + fr) * 32 + fq * 8);
#pragma unroll
        for (int mi = 0; mi < 4; ++mi)
#pragma unroll
          for (int ni = 0; ni < 8; ++ni)
            acc[mi][ni] = mfma16(af[mi], bfv[ni], acc[mi][ni]);
      };

      // prologue: fill the 4-slot ring (16 outstanding loads/thread)
      stage(0); stage(1); stage(2); stage(3);

      // main: wait only for the oldest stage (4 loads) -> 12 may stay in flight
#pragma unroll 1
      for (int k = 0; k < 60; ++k) {
        asm volatile("s_waitcnt vmcnt(12)" ::: "memory");
        GBAR();
        __builtin_amdgcn_sched_barrier(0);
        compute(k);
        __builtin_amdgcn_sched_barrier(0);
        GBAR();
        stage(k + 4);                        // k+4 <= 63
      }
      // tail: descending waits (no new stages; outstanding shrinks by 4 per iter)
#define GTAIL(K, WAITS)                                          \
      asm volatile("s_waitcnt vmcnt(" WAITS ")" ::: "memory");   \
      GBAR();                                                    \
      __builtin_amdgcn_sched_barrier(0);                         \
      compute(K);                                                \
      __builtin_amdgcn_sched_barrier(0);                         \
      GBAR();
      GTAIL(60, "12") GTAIL(61, "8") GTAIL(62, "4") GTAIL(63, "0")
#undef GTAIL

      // epilogue -> gxT layout (same as layer-0 GEMM); guard row<9600 (band 37 half)
#pragma unroll
      for (int ni = 0; ni < 8; ++ni) {
        int col = n0 + wn * 128 + ni * 16 + fr;
        float bv = gbias[col];
        int dirv = col >> 12, grow = col & (NG - 1);
        int gg = grow >> 10, uu = grow & 1023;
        bf16* base = (bf16*)gxT + ((size_t)dirv * 1200 + gg) * 32768 + uu;
#pragma unroll
        for (int mi = 0; mi < 4; ++mi) {
#pragma unroll
          for (int j = 0; j < 4; ++j) {
            int row = m0 + wm * 64 + mi * 16 + fq * 4 + j;
            if (row < MROWS) {
              int tt = row >> 5, b = row & 31;
              base[(size_t)tt * 131072 + b * 1024] = (bf16)(acc[mi][ni][j] + bv);
            }
          }
        }
      }
    }
    return;
  }

  // ================= recurrence role: blocks 0..63 (r10, proven) =================
  const int dir = bid >> 5;
  const int rank = bid & 31;
  const int u0 = rank << 5;
  const int w = tid >> 6, lane = tid & 63;
  const int fr = lane & 15, fq = lane >> 4;
  const int kh = w >> 1, rh = w & 1;

  // ---- weights -> registers (64 rows x K=256 per wave = 128 regs/lane), pinned ----
  f32x4 wf[32];
#pragma unroll
  for (int rg = 0; rg < 4; ++rg) {
    int rowb = rh * 64 + rg * 16 + fr;  // block gate-row 0..127 (= g*32 + u_local)
    const bf16* Wp = whh + ((size_t)dir * 4096 + (rowb >> 5) * 1024 + u0 + (rowb & 31)) * 1024
                     + kh * 256 + fq * 8;
#pragma unroll
    for (int it = 0; it < 8; ++it) wf[rg * 8 + it] = *(const f32x4*)(Wp + it * 32);
  }
#pragma unroll
  for (int i = 0; i < 32; ++i) asm volatile("" : "+v"(wf[i]));

  // ---- cell state in registers; c init = h0 (reference's cn=hn bug) ----
  const int b_pt = tid >> 4;           // batch 0..31
  const int ul_pt = (tid & 15) << 1;   // local unit 0,2,..,30
  const int ug_pt = u0 + ul_pt;
  const size_t soff = ((size_t)layer * 2 + dir) * 32768 + (size_t)b_pt * 1024 + ug_pt;
  float c0 = h0[soff], c1 = h0[soff + 1];
  float hl0 = 0.f, hl1 = 0.f;

  // gx DMA mapping: thread -> (gate, b, 16B quarter)
  const int gg = tid >> 7, sub = tid & 127;
  const size_t gx_base0 = ((size_t)dir * 1200 + gg) * 32768
                          + (size_t)(sub >> 2) * 1024 + u0 + (sub & 3) * 8;

  // h-stage source offsets (t-invariant): linear LDS dest, inverse-swizzled source
  int srcoff[8];
#pragma unroll
  for (int r = 0; r < 8; ++r) {
    int d = r * 8192 + tid * 16;
    int row = d >> 11, colb = d & 2047;
    srcoff[r] = row * 2048 + (colb ^ ((row & 7) << 4));
  }
  const int swz = (fr & 7) << 4;

  // ---- prologue: gx(0) DMA into buffer 0 ----
  {
    const int ts0 = dir ? (T_SEQ - 1) : 0;
    gload_lds16(gxT + gx_base0 + (size_t)ts0 * 131072, GXL + tid * 16);
  }

#pragma unroll 1
  for (int t = 0; t < T_SEQ; ++t) {
    const int tseq = dir ? (T_SEQ - 1 - t) : t;

    // ---- barrier: all same-dir blocks published h(t-1) ----
    if (tid < 32) {
      while (__hip_atomic_load(&flags[dir * 32 + tid], __ATOMIC_RELAXED,
                               __HIP_MEMORY_SCOPE_AGENT) < t)
        __builtin_amdgcn_s_sleep(1);
    }
    __syncthreads();

    // ---- stage h(dir) 64KB -> LDS via coherence-point bypass loads ----
    const char* hsrc = (const char*)hbuf + (((size_t)(t & 1) * 2 + dir) << 16);
#pragma unroll
    for (int r = 0; r < 8; ++r)
      gload_lds16_cc(hsrc + srcoff[r], smem_ + r * 8192 + tid * 16);
    asm volatile("s_waitcnt vmcnt(0)" ::: "memory");
    __syncthreads();

    // ---- matvec: K-split-4, 64 MFMA from LDS(h) x reg(W) ----
    f32x4 acc[4][2] = {};
    const char* hb0 = smem_ + fr * 2048;
#pragma unroll
    for (int it = 0; it < 8; ++it) {
      int col = kh * 512 + it * 64 + fq * 16;
      bf16x8 ha0 = *(const bf16x8*)(hb0 + (col ^ swz));
      bf16x8 ha1 = *(const bf16x8*)(hb0 + 32768 + (col ^ swz));
#pragma unroll
      for (int rg = 0; rg < 4; ++rg) {
        bf16x8 wv = __builtin_bit_cast(bf16x8, wf[rg * 8 + it]);
        acc[rg][0] = mfma16(ha0, wv, acc[rg][0]);
        acc[rg][1] = mfma16(ha1, wv, acc[rg][1]);
      }
    }
    __syncthreads();  // all waves done reading h tile; EX aliases it

    // ---- exchange K-partials via LDS (f32, stride 33) ----
#pragma unroll
    for (int rg = 0; rg < 4; ++rg) {
      int rowb = rh * 64 + rg * 16 + fr;
      float* exr = EX + (size_t)(kh * 128 + rowb) * 33;
#pragma unroll
      for (int j = 0; j < 4; ++j) {
        exr[fq * 4 + j]      = acc[rg][0][j];
        exr[16 + fq * 4 + j] = acc[rg][1][j];
      }
    }
    __syncthreads();

    // ---- pointwise: 2 (b,u) pairs/thread; sum 4 K-partials + gx(LDS) ----
    const bf16* gxb = (const bf16*)(GXL + (t & 1) * 8192);
    float hv[2]; float cc[2] = {c0, c1};
#pragma unroll
    for (int q = 0; q < 2; ++q) {
      int ul = ul_pt + q;
      float gt[4];
#pragma unroll
      for (int g2 = 0; g2 < 4; ++g2) {
        int rowb = g2 * 32 + ul;
        float s = EX[(size_t)(0 * 128 + rowb) * 33 + b_pt]
                + EX[(size_t)(1 * 128 + rowb) * 33 + b_pt]
                + EX[(size_t)(2 * 128 + rowb) * 33 + b_pt]
                + EX[(size_t)(3 * 128 + rowb) * 33 + b_pt];
        gt[g2] = s + (float)gxb[(g2 * 32 + b_pt) * 32 + ul];
      }
      float iv = fminf(fmaxf(__builtin_fmaf(0.2f, gt[0], 0.5f), 0.f), 1.f);
      float fv = fminf(fmaxf(__builtin_fmaf(0.2f, gt[1], 0.5f), 0.f), 1.f);
      float gv = fminf(fmaxf(gt[2], -1.f), 1.f);
      float ov = fminf(fmaxf(__builtin_fmaf(0.2f, gt[3], 0.5f), 0.f), 1.f);
      float c = fv * cc[q] + iv * gv;
      cc[q] = c;
      hv[q] = ov * fminf(fmaxf(c, -1.f), 1.f);
    }
    c0 = cc[0]; c1 = cc[1]; hl0 = hv[0]; hl1 = hv[1];

    // ---- publish h (volatile write-through), drain, flag ----
    unsigned hp;
    { union { bf16 h[2]; unsigned u; } pk; pk.h[0] = (bf16)hv[0]; pk.h[1] = (bf16)hv[1]; hp = pk.u; }
    volatile unsigned* hdst =
        (volatile unsigned*)((char*)hbuf + (((size_t)((t + 1) & 1) * 2 + dir) << 16))
        + (((size_t)b_pt * 1024 + ug_pt) >> 1);
    *hdst = hp;
    asm volatile("s_waitcnt vmcnt(0)" ::: "memory");
    __syncthreads();   // all h stores at coherence point before flag release
    if (tid == 0)
      __hip_atomic_store(&flags[bid], t + 1, __ATOMIC_RELAXED, __HIP_MEMORY_SCOPE_AGENT);

    // ---- off-path: y stores (write-through: gemm consumers read via L3)
    //      + gx(t+1) prefetch; both drained by NEXT step's publish vmcnt ----
    if (yout) {
      volatile unsigned* yd =
          (volatile unsigned*)((char*)yout
              + (((size_t)tseq * 32 + b_pt) * 2048 + dir * 1024 + ug_pt) * 2);
      *yd = hp;
    } else {
      float* yd = dout + ((size_t)tseq * 32 + b_pt) * 2048 + dir * 1024 + ug_pt;
      yd[0] = hv[0]; yd[1] = hv[1];
    }
    if (t + 1 < T_SEQ) {
      const int tn = dir ? (T_SEQ - 2 - t) : (t + 1);
      gload_lds16(gxT + gx_base0 + (size_t)tn * 131072,
                  GXL + ((t + 1) & 1) * 8192 + tid * 16);
    }
  }

  // ---- final (h,c) states; drain everything; release terminal flag (>= all thr) ----
  dout[OUT_Y + soff] = hl0;
  dout[OUT_Y + soff + 1] = hl1;
  dout[OUT_Y + HN_SZ + soff] = c0;
  dout[OUT_Y + HN_SZ + soff + 1] = c1;
  asm volatile("s_waitcnt vmcnt(0)" ::: "memory");
  __syncthreads();
  if (tid == 0)
    __hip_atomic_store(&flags[bid], 302, __ATOMIC_RELAXED, __HIP_MEMORY_SCOPE_AGENT);
}

// ---------------- host launcher ----------------
extern "C" void kernel_launch(void* const* d_in, const int* in_sizes, int n_in,
                              void* d_out, int out_size, void* d_ws, size_t ws_size,
                              hipStream_t stream) {
  const float* x     = (const float*)d_in[0];
  const float* h0    = (const float*)d_in[1];
  // d_in[2] = c0: unused (reference init bug: cn = hn = h0)
  const float* w_ih0 = (const float*)d_in[3];
  const float* w_hh0 = (const float*)d_in[4];
  const float* b_ih0 = (const float*)d_in[5];
  const float* b_hh0 = (const float*)d_in[6];
  const float* w_ihL = (const float*)d_in[7];
  const float* w_hhL = (const float*)d_in[8];
  const float* b_ihL = (const float*)d_in[9];
  const float* b_hhL = (const float*)d_in[10];
  float* dout = (float*)d_out;
  char* ws = (char*)d_ws;

  // ---- workspace carve (bytes) ----
  const size_t OFF_XB   = 0;                         // bf16 [9600][320]
  const size_t OFF_WIH0 = 6144000;                   // bf16 [8192][320]
  const size_t OFF_WIHL = 11386880;                  // bf16 [2][8192][2048]
  const size_t OFF_WHH  = 78495744;                  // bf16 [6][4096][1024]
  const size_t OFF_BSUM = 128827392;                 // f32  [6][4096]
  const size_t OFF_GX   = 128925696;                 // bf16 [2][300][4][32][1024]
  const size_t OFF_Y0   = 286212096;                 // bf16 [9600][2048]
  const size_t OFF_Y1   = 325533696;                 // bf16 [9600][2048]
  const size_t OFF_HBF  = 364855296;                 // bf16 [2 par][2 dir][32][1024]
  const size_t OFF_FLG  = 365117440;                 // int  [64]

  bf16*  xb    = (bf16*)(ws + OFF_XB);
  bf16*  wih0b = (bf16*)(ws + OFF_WIH0);
  bf16*  wihLb = (bf16*)(ws + OFF_WIHL);
  bf16*  whhb  = (bf16*)(ws + OFF_WHH);
  float* bsum  = (float*)(ws + OFF_BSUM);
  bf16*  gx    = (bf16*)(ws + OFF_GX);
  bf16*  y0    = (bf16*)(ws + OFF_Y0);
  bf16*  y1    = (bf16*)(ws + OFF_Y1);
  bf16*  hbuf  = (bf16*)(ws + OFF_HBF);
  int*   flags = (int*)(ws + OFF_FLG);

  auto cvt = [&](const float* s, bf16* d, size_t n) {
    int n8 = (int)(n / 8);
    int grid = (n8 + 255) / 256; if (grid > 2048) grid = 2048;
    k_cvt<<<grid, 256, 0, stream>>>(s, d, n8);
  };

  cvt(x,     xb,    (size_t)MROWS * DIN);
  cvt(w_ih0, wih0b, (size_t)2 * NG * DIN);
  cvt(w_ihL, wihLb, (size_t)2 * 2 * NG * 2048);
  cvt(w_hh0, whhb,  (size_t)2 * NG * NH);
  cvt(w_hhL, whhb + (size_t)2 * NG * NH, (size_t)4 * NG * NH);
  k_bsum<<<96, 256, 0, stream>>>(b_ih0, b_hh0, b_ihL, b_hhL, bsum);

  // layer-0 gx GEMM (input x available immediately)
  k_gemm_gx<<<dim3(64, 75), 256, 0, stream>>>(xb, wih0b, bsum, gx, DIN);

  for (int l = 0; l < 3; ++l) {
    k_init<<<256, 256, 0, stream>>>(h0, hbuf, flags, l);

    const bf16* whh_l = whhb + (size_t)l * 2 * NG * NH;
    bf16* yout = (l == 0) ? y0 : (l == 1 ? y1 : nullptr);
    const int ngemm = (l < 2) ? 192 : 0;
    const bf16* gB = wihLb + (size_t)l * 2 * NG * 2048;   // next layer's w_ih
    const float* gbias = bsum + (size_t)(l + 1) * 2 * NG;
    k_rec<<<64 + ngemm, 512, 0, stream>>>(whh_l, gx, h0, hbuf, flags, yout, dout, l,
                                          gB, gbias, ngemm);
  }
  (void)in_sizes; (void)n_in; (void)out_size; (void)ws_size;
}

// Round 18
// 4047.332 us; speedup vs baseline: 1.2636x; 1.1627x over previous
//
#include <hip/hip_runtime.h>

typedef __bf16 bf16;
typedef __attribute__((ext_vector_type(8))) __bf16 bf16x8;
typedef __attribute__((ext_vector_type(4))) float f32x4;

#define GLOBAL_AS __attribute__((address_space(1)))
#define LDS_AS __attribute__((address_space(3)))

__device__ __forceinline__ void gload_lds16(const void* g, void* l) {
  __builtin_amdgcn_global_load_lds((const GLOBAL_AS void*)g, (LDS_AS void*)l, 16, 0, 0);
}
// cache-bypassing variant (sc0|sc1 = system scope): coherent-read-through
__device__ __forceinline__ void gload_lds16_cc(const void* g, void* l) {
  __builtin_amdgcn_global_load_lds((const GLOBAL_AS void*)g, (LDS_AS void*)l, 16, 0, 0x11);
}

__device__ __forceinline__ f32x4 mfma16(bf16x8 a, bf16x8 b, f32x4 c) {
  return __builtin_amdgcn_mfma_f32_16x16x32_bf16(a, b, c, 0, 0, 0);
}

// hardware barrier + compiler memory fence
#define GBAR() asm volatile("s_barrier" ::: "memory")

// ---------------- constants ----------------
#define T_SEQ 300
#define NBATCH 32
#define DIN 320
#define NH 1024
#define NG 4096              // 4*NH
#define MROWS 9600           // T_SEQ*NBATCH
#define OUT_Y 19660800       // T*B*2H
#define HN_SZ 196608         // 6*32*1024
#define FPAD 32              // flag padding: one 128B line per flag

// ---------------- f32 -> bf16 convert ----------------
__global__ __launch_bounds__(256) void k_cvt(const float* __restrict__ src,
                                             bf16* __restrict__ dst, int n8) {
  int stride = gridDim.x * blockDim.x;
  for (int i = blockIdx.x * blockDim.x + threadIdx.x; i < n8; i += stride) {
    const float* s = src + (size_t)i * 8;
    f32x4 a = *(const f32x4*)s;
    f32x4 b = *(const f32x4*)(s + 4);
    bf16x8 o;
#pragma unroll
    for (int j = 0; j < 4; ++j) { o[j] = (bf16)a[j]; o[j + 4] = (bf16)b[j]; }
    *(bf16x8*)(dst + (size_t)i * 8) = o;
  }
}

// ---------------- bias sums: bsum[l][dir][4096] = b_ih + b_hh ----------------
__global__ __launch_bounds__(256) void k_bsum(const float* __restrict__ bih0,
                                              const float* __restrict__ bhh0,
                                              const float* __restrict__ bihL,
                                              const float* __restrict__ bhhL,
                                              float* __restrict__ bsum) {
  int i = blockIdx.x * 256 + threadIdx.x;  // n = 6*4096 = 24576
  if (i < 2 * NG) bsum[i] = bih0[i] + bhh0[i];
  else            bsum[i] = bihL[i - 2 * NG] + bhhL[i - 2 * NG];
}

// ---------------- GX GEMM (layer 0 only): gxT[dir][t][g][b][u] ----------------
__global__ __launch_bounds__(256) void k_gemm_gx(const bf16* __restrict__ A,
                                                 const bf16* __restrict__ Bw,
                                                 const float* __restrict__ bias,
                                                 bf16* __restrict__ gxout, int K) {
  __shared__ bf16 As[128 * 32];
  __shared__ bf16 Bs[128 * 32];
  const int t = threadIdx.x;
  const int m0 = blockIdx.y * 128, n0 = blockIdx.x * 128;
  const int lane = t & 63, wid = t >> 6;
  const int wr = wid >> 1, wc = wid & 1;
  const int fr = lane & 15, fq = lane >> 4;
  f32x4 acc[4][4] = {};
  for (int k0 = 0; k0 < K; k0 += 32) {
#pragma unroll
    for (int r = 0; r < 2; ++r) {
      int idx = r * 256 + t;
      int row = idx >> 2, kk = (idx & 3) * 8;
      gload_lds16(A + (size_t)(m0 + row) * K + k0 + kk, As + (size_t)idx * 8);
      gload_lds16(Bw + (size_t)(n0 + row) * K + k0 + kk, Bs + (size_t)idx * 8);
    }
    asm volatile("s_waitcnt vmcnt(0)" ::: "memory");
    __syncthreads();
    bf16x8 af[4], bf_[4];
#pragma unroll
    for (int i2 = 0; i2 < 4; ++i2) {
      af[i2]  = *(const bf16x8*)(As + (wr * 64 + i2 * 16 + fr) * 32 + fq * 8);
      bf_[i2] = *(const bf16x8*)(Bs + (wc * 64 + i2 * 16 + fr) * 32 + fq * 8);
    }
#pragma unroll
    for (int mi = 0; mi < 4; ++mi)
#pragma unroll
      for (int ni = 0; ni < 4; ++ni)
        acc[mi][ni] = mfma16(af[mi], bf_[ni], acc[mi][ni]);
    __syncthreads();
  }
#pragma unroll
  for (int ni = 0; ni < 4; ++ni) {
    int col = n0 + wc * 64 + ni * 16 + fr;
    float bv = bias[col];
    int dir = col >> 12, grow = col & (NG - 1);
    int gg = grow >> 10, uu = grow & 1023;
    bf16* base = gxout + ((size_t)dir * 300 * 4 + gg) * 32768 + uu;
#pragma unroll
    for (int mi = 0; mi < 4; ++mi) {
#pragma unroll
      for (int j = 0; j < 4; ++j) {
        int row = m0 + wr * 64 + mi * 16 + fq * 4 + j;
        int tt = row >> 5, b = row & 31;
        base[(size_t)tt * 131072 + b * 1024] = (bf16)(acc[mi][ni][j] + bv);
      }
    }
  }
}

// ---------------- per-layer init: h buffer (par 0) + padded flags ----------------
__global__ __launch_bounds__(256) void k_init(const float* __restrict__ h0,
                                              bf16* __restrict__ hbuf,
                                              int* __restrict__ flags, int layer) {
  int i = blockIdx.x * 256 + threadIdx.x;  // 65536 = [2 dir][32][1024]
  hbuf[i] = (bf16)h0[(size_t)layer * 65536 + i];
  if (blockIdx.x == 0) {
    for (int j = threadIdx.x; j < 64 * FPAD; j += 256) flags[j] = 0;
  }
}

// ---------------- fused persistent kernel: recurrence + next-layer GEMM ----------------
// grid = 64 (+192 gemm) blocks x 512 threads; 128KB static LDS -> 1 block/CU -> all
// co-resident (grid <= 256 CUs). Blocks 0..63: r10 rec (proven ~1220 us/layer).
// Blocks 64..255: flag-gated 256x256 GEMM tiles (BK=32, 4-slot counted-vmcnt ring).
// r18 change: flags padded to one 128B line each + GEMM poll sleep 32->200.
// Mechanism: 12288 GEMM poller threads at 0.85us period hammered TWO L3 lines
// (~14k same-line loads/us); rec's per-step flag store/poll queued behind -> +30%
// step time. Padding (64 lines) + 13.6us period cuts per-line load ~500x.
__global__ __launch_bounds__(512, 1) void k_rec(
    const bf16* __restrict__ whh,   // [2][4096][1024] (this layer)
    const bf16* __restrict__ gxT,   // [2][300][4][32][1024] bf16, biases folded
    const float* __restrict__ h0,   // [6][32][1024]
    bf16* __restrict__ hbuf,        // [2 par][2 dir][32][1024]
    int* __restrict__ flags,        // [64*FPAD], zeroed by k_init
    bf16* __restrict__ yout,        // [9600][2048] or null (layer 2)
    float* __restrict__ dout,
    int layer,
    const bf16* __restrict__ gB,    // next-layer w_ih bf16 [8192][2048] (gemm role)
    const float* __restrict__ gbias,// next-layer bias sums [8192]
    int ngemm) {
  __shared__ char smem_[131072];
  // rec role:  [0..65536) h tile | EX f32 [4][128][33] aliases | [67584..83968) GXL 2x8KB
  // gemm role: 4-slot ring, slot s at [s*32768): As 256x32 bf16 (16KB) | Bs 256x32 (16KB)
  float* EX = (float*)smem_;
  char* GXL = smem_ + 67584;

  const int tid = threadIdx.x;
  const int bid = blockIdx.x;

  // ================= GEMM role: blocks 64..63+ngemm =================
  if (bid >= 64) {
    const int gid = bid - 64;
    if (gid >= ngemm) return;
    const int lane = tid & 63, wid = tid >> 6;
    const int wm = wid >> 1, wn = wid & 1;     // 4m x 2n wave grid; wave tile 64x128
    const int fr = lane & 15, fq = lane >> 4;
    // staging: 512 threads sweep a [128][32] half-tile; LDS addr = base + tid*16
    // (global_load_lds HW writes wave-uniform-base + lane*16 — must match, m104/m108)
    const int srow = tid >> 2;                 // 0..127
    const int scol = (tid & 3) * 8;            // element col 0,8,16,24
    const int l16 = tid * 16;                  // lane-contiguous LDS byte offset
#pragma unroll 1
    for (int i = 0; i < 7; ++i) {
      const int lin = i * 192 + gid;           // 1216 tiles = 38 m x 32 n
      if (lin >= 1216) break;
      const int n0 = (lin & 31) << 8;          // fixed per block (192 % 32 == 0)
      const int mrank = lin >> 5;              // readiness rank: center-out m
      const int m = (mrank & 1) ? (19 + (mrank >> 1)) : (18 - (mrank >> 1));
      const int m0 = m << 8;
      int ra = 8 * m + 7; if (ra > 299) ra = 299;
      const int rb = 299 - 8 * m;
      const int thr = (ra > rb ? ra : rb) + 2; // y(band) drained & gx(band) dead
      if (tid < 64) {
        while (__hip_atomic_load(&flags[tid * FPAD], __ATOMIC_RELAXED,
                                 __HIP_MEMORY_SCOPE_AGENT) < thr)
          __builtin_amdgcn_s_sleep(200);       // ~13.6us: off rec's flag lines
      }
      __syncthreads();
      // acquire: invalidate stale local L1/L2 so cached y reads see rec's stores
      __builtin_amdgcn_fence(__ATOMIC_ACQUIRE, "agent");

      // band-37 A over-read past row 9599 lands in adjacent ws regions: safe
      const bf16* ArowL = yout + (size_t)(m0 + srow) * 2048 + scol;
      const bf16* ArowH = yout + (size_t)(m0 + 128 + srow) * 2048 + scol;
      const bf16* BrowL = gB + (size_t)(n0 + srow) * 2048 + scol;
      const bf16* BrowH = gB + (size_t)(n0 + 128 + srow) * 2048 + scol;

      auto stage = [&](int ks) {
        char* buf = smem_ + (ks & 3) * 32768;
        gload_lds16(ArowL + ks * 32, buf + l16);            // A rows   0..127
        gload_lds16(ArowH + ks * 32, buf + 8192 + l16);     // A rows 128..255
        gload_lds16(BrowL + ks * 32, buf + 16384 + l16);    // B rows   0..127
        gload_lds16(BrowH + ks * 32, buf + 24576 + l16);    // B rows 128..255
      };

      f32x4 acc[4][8] = {};
      auto compute = [&](int k) {
        const bf16* As = (const bf16*)(smem_ + (k & 3) * 32768);
        const bf16* Bs = As + 8192;
        bf16x8 af[4], bfv[8];
#pragma unroll
        for (int i2 = 0; i2 < 4; ++i2)
          af[i2] = *(const bf16x8*)(As + (wm * 64 + i2 * 16 + fr) * 32 + fq * 8);
#pragma unroll
        for (int i2 = 0; i2 < 8; ++i2)
          bfv[i2] = *(const bf16x8*)(Bs + (wn * 128 + i2 * 16 + fr) * 32 + fq * 8);
#pragma unroll
        for (int mi = 0; mi < 4; ++mi)
#pragma unroll
          for (int ni = 0; ni < 8; ++ni)
            acc[mi][ni] = mfma16(af[mi], bfv[ni], acc[mi][ni]);
      };

      // prologue: fill the 4-slot ring (16 outstanding loads/thread)
      stage(0); stage(1); stage(2); stage(3);

      // main: wait only for the oldest stage (4 loads) -> 12 may stay in flight
#pragma unroll 1
      for (int k = 0; k < 60; ++k) {
        asm volatile("s_waitcnt vmcnt(12)" ::: "memory");
        GBAR();
        __builtin_amdgcn_sched_barrier(0);
        compute(k);
        __builtin_amdgcn_sched_barrier(0);
        GBAR();
        stage(k + 4);                        // k+4 <= 63
      }
      // tail: descending waits (no new stages; outstanding shrinks by 4 per iter)
#define GTAIL(K, WAITS)                                          \
      asm volatile("s_waitcnt vmcnt(" WAITS ")" ::: "memory");   \
      GBAR();                                                    \
      __builtin_amdgcn_sched_barrier(0);                         \
      compute(K);                                                \
      __builtin_amdgcn_sched_barrier(0);                         \
      GBAR();
      GTAIL(60, "12") GTAIL(61, "8") GTAIL(62, "4") GTAIL(63, "0")
#undef GTAIL

      // epilogue -> gxT layout (same as layer-0 GEMM); guard row<9600 (band 37 half)
#pragma unroll
      for (int ni = 0; ni < 8; ++ni) {
        int col = n0 + wn * 128 + ni * 16 + fr;
        float bv = gbias[col];
        int dirv = col >> 12, grow = col & (NG - 1);
        int gg = grow >> 10, uu = grow & 1023;
        bf16* base = (bf16*)gxT + ((size_t)dirv * 1200 + gg) * 32768 + uu;
#pragma unroll
        for (int mi = 0; mi < 4; ++mi) {
#pragma unroll
          for (int j = 0; j < 4; ++j) {
            int row = m0 + wm * 64 + mi * 16 + fq * 4 + j;
            if (row < MROWS) {
              int tt = row >> 5, b = row & 31;
              base[(size_t)tt * 131072 + b * 1024] = (bf16)(acc[mi][ni][j] + bv);
            }
          }
        }
      }
    }
    return;
  }

  // ================= recurrence role: blocks 0..63 (r10, proven) =================
  const int dir = bid >> 5;
  const int rank = bid & 31;
  const int u0 = rank << 5;
  const int w = tid >> 6, lane = tid & 63;
  const int fr = lane & 15, fq = lane >> 4;
  const int kh = w >> 1, rh = w & 1;

  // ---- weights -> registers (64 rows x K=256 per wave = 128 regs/lane), pinned ----
  f32x4 wf[32];
#pragma unroll
  for (int rg = 0; rg < 4; ++rg) {
    int rowb = rh * 64 + rg * 16 + fr;  // block gate-row 0..127 (= g*32 + u_local)
    const bf16* Wp = whh + ((size_t)dir * 4096 + (rowb >> 5) * 1024 + u0 + (rowb & 31)) * 1024
                     + kh * 256 + fq * 8;
#pragma unroll
    for (int it = 0; it < 8; ++it) wf[rg * 8 + it] = *(const f32x4*)(Wp + it * 32);
  }
#pragma unroll
  for (int i = 0; i < 32; ++i) asm volatile("" : "+v"(wf[i]));

  // ---- cell state in registers; c init = h0 (reference's cn=hn bug) ----
  const int b_pt = tid >> 4;           // batch 0..31
  const int ul_pt = (tid & 15) << 1;   // local unit 0,2,..,30
  const int ug_pt = u0 + ul_pt;
  const size_t soff = ((size_t)layer * 2 + dir) * 32768 + (size_t)b_pt * 1024 + ug_pt;
  float c0 = h0[soff], c1 = h0[soff + 1];
  float hl0 = 0.f, hl1 = 0.f;

  // gx DMA mapping: thread -> (gate, b, 16B quarter)
  const int gg = tid >> 7, sub = tid & 127;
  const size_t gx_base0 = ((size_t)dir * 1200 + gg) * 32768
                          + (size_t)(sub >> 2) * 1024 + u0 + (sub & 3) * 8;

  // h-stage source offsets (t-invariant): linear LDS dest, inverse-swizzled source
  int srcoff[8];
#pragma unroll
  for (int r = 0; r < 8; ++r) {
    int d = r * 8192 + tid * 16;
    int row = d >> 11, colb = d & 2047;
    srcoff[r] = row * 2048 + (colb ^ ((row & 7) << 4));
  }
  const int swz = (fr & 7) << 4;

  // ---- prologue: gx(0) DMA into buffer 0 ----
  {
    const int ts0 = dir ? (T_SEQ - 1) : 0;
    gload_lds16(gxT + gx_base0 + (size_t)ts0 * 131072, GXL + tid * 16);
  }

#pragma unroll 1
  for (int t = 0; t < T_SEQ; ++t) {
    const int tseq = dir ? (T_SEQ - 1 - t) : t;

    // ---- barrier: all same-dir blocks published h(t-1); padded flag lines ----
    if (tid < 32) {
      while (__hip_atomic_load(&flags[(dir * 32 + tid) * FPAD], __ATOMIC_RELAXED,
                               __HIP_MEMORY_SCOPE_AGENT) < t)
        __builtin_amdgcn_s_sleep(1);
    }
    __syncthreads();

    // ---- stage h(dir) 64KB -> LDS via coherence-point bypass loads ----
    const char* hsrc = (const char*)hbuf + (((size_t)(t & 1) * 2 + dir) << 16);
#pragma unroll
    for (int r = 0; r < 8; ++r)
      gload_lds16_cc(hsrc + srcoff[r], smem_ + r * 8192 + tid * 16);
    asm volatile("s_waitcnt vmcnt(0)" ::: "memory");
    __syncthreads();

    // ---- matvec: K-split-4, 64 MFMA from LDS(h) x reg(W) ----
    f32x4 acc[4][2] = {};
    const char* hb0 = smem_ + fr * 2048;
#pragma unroll
    for (int it = 0; it < 8; ++it) {
      int col = kh * 512 + it * 64 + fq * 16;
      bf16x8 ha0 = *(const bf16x8*)(hb0 + (col ^ swz));
      bf16x8 ha1 = *(const bf16x8*)(hb0 + 32768 + (col ^ swz));
#pragma unroll
      for (int rg = 0; rg < 4; ++rg) {
        bf16x8 wv = __builtin_bit_cast(bf16x8, wf[rg * 8 + it]);
        acc[rg][0] = mfma16(ha0, wv, acc[rg][0]);
        acc[rg][1] = mfma16(ha1, wv, acc[rg][1]);
      }
    }
    __syncthreads();  // all waves done reading h tile; EX aliases it

    // ---- exchange K-partials via LDS (f32, stride 33) ----
#pragma unroll
    for (int rg = 0; rg < 4; ++rg) {
      int rowb = rh * 64 + rg * 16 + fr;
      float* exr = EX + (size_t)(kh * 128 + rowb) * 33;
#pragma unroll
      for (int j = 0; j < 4; ++j) {
        exr[fq * 4 + j]      = acc[rg][0][j];
        exr[16 + fq * 4 + j] = acc[rg][1][j];
      }
    }
    __syncthreads();

    // ---- pointwise: 2 (b,u) pairs/thread; sum 4 K-partials + gx(LDS) ----
    const bf16* gxb = (const bf16*)(GXL + (t & 1) * 8192);
    float hv[2]; float cc[2] = {c0, c1};
#pragma unroll
    for (int q = 0; q < 2; ++q) {
      int ul = ul_pt + q;
      float gt[4];
#pragma unroll
      for (int g2 = 0; g2 < 4; ++g2) {
        int rowb = g2 * 32 + ul;
        float s = EX[(size_t)(0 * 128 + rowb) * 33 + b_pt]
                + EX[(size_t)(1 * 128 + rowb) * 33 + b_pt]
                + EX[(size_t)(2 * 128 + rowb) * 33 + b_pt]
                + EX[(size_t)(3 * 128 + rowb) * 33 + b_pt];
        gt[g2] = s + (float)gxb[(g2 * 32 + b_pt) * 32 + ul];
      }
      float iv = fminf(fmaxf(__builtin_fmaf(0.2f, gt[0], 0.5f), 0.f), 1.f);
      float fv = fminf(fmaxf(__builtin_fmaf(0.2f, gt[1], 0.5f), 0.f), 1.f);
      float gv = fminf(fmaxf(gt[2], -1.f), 1.f);
      float ov = fminf(fmaxf(__builtin_fmaf(0.2f, gt[3], 0.5f), 0.f), 1.f);
      float c = fv * cc[q] + iv * gv;
      cc[q] = c;
      hv[q] = ov * fminf(fmaxf(c, -1.f), 1.f);
    }
    c0 = cc[0]; c1 = cc[1]; hl0 = hv[0]; hl1 = hv[1];

    // ---- publish h (volatile write-through), drain, flag ----
    unsigned hp;
    { union { bf16 h[2]; unsigned u; } pk; pk.h[0] = (bf16)hv[0]; pk.h[1] = (bf16)hv[1]; hp = pk.u; }
    volatile unsigned* hdst =
        (volatile unsigned*)((char*)hbuf + (((size_t)((t + 1) & 1) * 2 + dir) << 16))
        + (((size_t)b_pt * 1024 + ug_pt) >> 1);
    *hdst = hp;
    asm volatile("s_waitcnt vmcnt(0)" ::: "memory");
    __syncthreads();   // all h stores at coherence point before flag release
    if (tid == 0)
      __hip_atomic_store(&flags[bid * FPAD], t + 1, __ATOMIC_RELAXED, __HIP_MEMORY_SCOPE_AGENT);

    // ---- off-path: y stores (write-through: gemm consumers read via L3)
    //      + gx(t+1) prefetch; both drained by NEXT step's publish vmcnt ----
    if (yout) {
      volatile unsigned* yd =
          (volatile unsigned*)((char*)yout
              + (((size_t)tseq * 32 + b_pt) * 2048 + dir * 1024 + ug_pt) * 2);
      *yd = hp;
    } else {
      float* yd = dout + ((size_t)tseq * 32 + b_pt) * 2048 + dir * 1024 + ug_pt;
      yd[0] = hv[0]; yd[1] = hv[1];
    }
    if (t + 1 < T_SEQ) {
      const int tn = dir ? (T_SEQ - 2 - t) : (t + 1);
      gload_lds16(gxT + gx_base0 + (size_t)tn * 131072,
                  GXL + ((t + 1) & 1) * 8192 + tid * 16);
    }
  }

  // ---- final (h,c) states; drain everything; release terminal flag (>= all thr) ----
  dout[OUT_Y + soff] = hl0;
  dout[OUT_Y + soff + 1] = hl1;
  dout[OUT_Y + HN_SZ + soff] = c0;
  dout[OUT_Y + HN_SZ + soff + 1] = c1;
  asm volatile("s_waitcnt vmcnt(0)" ::: "memory");
  __syncthreads();
  if (tid == 0)
    __hip_atomic_store(&flags[bid * FPAD], 302, __ATOMIC_RELAXED, __HIP_MEMORY_SCOPE_AGENT);
}

// ---------------- host launcher ----------------
extern "C" void kernel_launch(void* const* d_in, const int* in_sizes, int n_in,
                              void* d_out, int out_size, void* d_ws, size_t ws_size,
                              hipStream_t stream) {
  const float* x     = (const float*)d_in[0];
  const float* h0    = (const float*)d_in[1];
  // d_in[2] = c0: unused (reference init bug: cn = hn = h0)
  const float* w_ih0 = (const float*)d_in[3];
  const float* w_hh0 = (const float*)d_in[4];
  const float* b_ih0 = (const float*)d_in[5];
  const float* b_hh0 = (const float*)d_in[6];
  const float* w_ihL = (const float*)d_in[7];
  const float* w_hhL = (const float*)d_in[8];
  const float* b_ihL = (const float*)d_in[9];
  const float* b_hhL = (const float*)d_in[10];
  float* dout = (float*)d_out;
  char* ws = (char*)d_ws;

  // ---- workspace carve (bytes) ----
  const size_t OFF_XB   = 0;                         // bf16 [9600][320]
  const size_t OFF_WIH0 = 6144000;                   // bf16 [8192][320]
  const size_t OFF_WIHL = 11386880;                  // bf16 [2][8192][2048]
  const size_t OFF_WHH  = 78495744;                  // bf16 [6][4096][1024]
  const size_t OFF_BSUM = 128827392;                 // f32  [6][4096]
  const size_t OFF_GX   = 128925696;                 // bf16 [2][300][4][32][1024]
  const size_t OFF_Y0   = 286212096;                 // bf16 [9600][2048]
  const size_t OFF_Y1   = 325533696;                 // bf16 [9600][2048]
  const size_t OFF_HBF  = 364855296;                 // bf16 [2 par][2 dir][32][1024]
  const size_t OFF_FLG  = 365117440;                 // int  [64*FPAD] (128B-padded)

  bf16*  xb    = (bf16*)(ws + OFF_XB);
  bf16*  wih0b = (bf16*)(ws + OFF_WIH0);
  bf16*  wihLb = (bf16*)(ws + OFF_WIHL);
  bf16*  whhb  = (bf16*)(ws + OFF_WHH);
  float* bsum  = (float*)(ws + OFF_BSUM);
  bf16*  gx    = (bf16*)(ws + OFF_GX);
  bf16*  y0    = (bf16*)(ws + OFF_Y0);
  bf16*  y1    = (bf16*)(ws + OFF_Y1);
  bf16*  hbuf  = (bf16*)(ws + OFF_HBF);
  int*   flags = (int*)(ws + OFF_FLG);

  auto cvt = [&](const float* s, bf16* d, size_t n) {
    int n8 = (int)(n / 8);
    int grid = (n8 + 255) / 256; if (grid > 2048) grid = 2048;
    k_cvt<<<grid, 256, 0, stream>>>(s, d, n8);
  };

  cvt(x,     xb,    (size_t)MROWS * DIN);
  cvt(w_ih0, wih0b, (size_t)2 * NG * DIN);
  cvt(w_ihL, wihLb, (size_t)2 * 2 * NG * 2048);
  cvt(w_hh0, whhb,  (size_t)2 * NG * NH);
  cvt(w_hhL, whhb + (size_t)2 * NG * NH, (size_t)4 * NG * NH);
  k_bsum<<<96, 256, 0, stream>>>(b_ih0, b_hh0, b_ihL, b_hhL, bsum);

  // layer-0 gx GEMM (input x available immediately)
  k_gemm_gx<<<dim3(64, 75), 256, 0, stream>>>(xb, wih0b, bsum, gx, DIN);

  for (int l = 0; l < 3; ++l) {
    k_init<<<256, 256, 0, stream>>>(h0, hbuf, flags, l);

    const bf16* whh_l = whhb + (size_t)l * 2 * NG * NH;
    bf16* yout = (l == 0) ? y0 : (l == 1 ? y1 : nullptr);
    const int ngemm = (l < 2) ? 192 : 0;
    const bf16* gB = wihLb + (size_t)l * 2 * NG * 2048;   // next layer's w_ih
    const float* gbias = bsum + (size_t)(l + 1) * 2 * NG;
    k_rec<<<64 + ngemm, 512, 0, stream>>>(whh_l, gx, h0, hbuf, flags, yout, dout, l,
                                          gB, gbias, ngemm);
  }
  (void)in_sizes; (void)n_in; (void)out_size; (void)ws_size;
}

// Round 19
// 3894.188 us; speedup vs baseline: 1.3133x; 1.0393x over previous
//
#include <hip/hip_runtime.h>

typedef __bf16 bf16;
typedef __attribute__((ext_vector_type(8))) __bf16 bf16x8;
typedef __attribute__((ext_vector_type(4))) float f32x4;

#define GLOBAL_AS __attribute__((address_space(1)))
#define LDS_AS __attribute__((address_space(3)))

__device__ __forceinline__ void gload_lds16(const void* g, void* l) {
  __builtin_amdgcn_global_load_lds((const GLOBAL_AS void*)g, (LDS_AS void*)l, 16, 0, 0);
}
// sc0-only (GLC): L1-bypass, served from local L2 — for same-XCD-fresh h reads
__device__ __forceinline__ void gload_lds16_sc0(const void* g, void* l) {
  __builtin_amdgcn_global_load_lds((const GLOBAL_AS void*)g, (LDS_AS void*)l, 16, 0, 0x1);
}

__device__ __forceinline__ f32x4 mfma16(bf16x8 a, bf16x8 b, f32x4 c) {
  return __builtin_amdgcn_mfma_f32_16x16x32_bf16(a, b, c, 0, 0, 0);
}

// hardware barrier + compiler memory fence
#define GBAR() asm volatile("s_barrier" ::: "memory")

// ---------------- constants ----------------
#define T_SEQ 300
#define NBATCH 32
#define DIN 320
#define NH 1024
#define NG 4096              // 4*NH
#define MROWS 9600           // T_SEQ*NBATCH
#define OUT_Y 19660800       // T*B*2H
#define HN_SZ 196608         // 6*32*1024
#define FPAD 32              // flag padding: one 128B line per flag
#define ELEC_A (64 * FPAD)       // election slot: dir0 XCD
#define ELEC_B (64 * FPAD + 8)   // election slot: dir1 XCD
#define ELEC_R0 (64 * FPAD + 16) // rank counter dir0
#define ELEC_R1 (64 * FPAD + 24) // rank counter dir1
#define ELEC_G (64 * FPAD + 32)  // gemm gid counter

// ---------------- f32 -> bf16 convert ----------------
__global__ __launch_bounds__(256) void k_cvt(const float* __restrict__ src,
                                             bf16* __restrict__ dst, int n8) {
  int stride = gridDim.x * blockDim.x;
  for (int i = blockIdx.x * blockDim.x + threadIdx.x; i < n8; i += stride) {
    const float* s = src + (size_t)i * 8;
    f32x4 a = *(const f32x4*)s;
    f32x4 b = *(const f32x4*)(s + 4);
    bf16x8 o;
#pragma unroll
    for (int j = 0; j < 4; ++j) { o[j] = (bf16)a[j]; o[j + 4] = (bf16)b[j]; }
    *(bf16x8*)(dst + (size_t)i * 8) = o;
  }
}

// ---------------- bias sums: bsum[l][dir][4096] = b_ih + b_hh ----------------
__global__ __launch_bounds__(256) void k_bsum(const float* __restrict__ bih0,
                                              const float* __restrict__ bhh0,
                                              const float* __restrict__ bihL,
                                              const float* __restrict__ bhhL,
                                              float* __restrict__ bsum) {
  int i = blockIdx.x * 256 + threadIdx.x;  // n = 6*4096 = 24576
  if (i < 2 * NG) bsum[i] = bih0[i] + bhh0[i];
  else            bsum[i] = bihL[i - 2 * NG] + bhhL[i - 2 * NG];
}

// ---------------- GX GEMM (layer 0 only): gxT[dir][t][g][b][u] ----------------
__global__ __launch_bounds__(256) void k_gemm_gx(const bf16* __restrict__ A,
                                                 const bf16* __restrict__ Bw,
                                                 const float* __restrict__ bias,
                                                 bf16* __restrict__ gxout, int K) {
  __shared__ bf16 As[128 * 32];
  __shared__ bf16 Bs[128 * 32];
  const int t = threadIdx.x;
  const int m0 = blockIdx.y * 128, n0 = blockIdx.x * 128;
  const int lane = t & 63, wid = t >> 6;
  const int wr = wid >> 1, wc = wid & 1;
  const int fr = lane & 15, fq = lane >> 4;
  f32x4 acc[4][4] = {};
  for (int k0 = 0; k0 < K; k0 += 32) {
#pragma unroll
    for (int r = 0; r < 2; ++r) {
      int idx = r * 256 + t;
      int row = idx >> 2, kk = (idx & 3) * 8;
      gload_lds16(A + (size_t)(m0 + row) * K + k0 + kk, As + (size_t)idx * 8);
      gload_lds16(Bw + (size_t)(n0 + row) * K + k0 + kk, Bs + (size_t)idx * 8);
    }
    asm volatile("s_waitcnt vmcnt(0)" ::: "memory");
    __syncthreads();
    bf16x8 af[4], bf_[4];
#pragma unroll
    for (int i2 = 0; i2 < 4; ++i2) {
      af[i2]  = *(const bf16x8*)(As + (wr * 64 + i2 * 16 + fr) * 32 + fq * 8);
      bf_[i2] = *(const bf16x8*)(Bs + (wc * 64 + i2 * 16 + fr) * 32 + fq * 8);
    }
#pragma unroll
    for (int mi = 0; mi < 4; ++mi)
#pragma unroll
      for (int ni = 0; ni < 4; ++ni)
        acc[mi][ni] = mfma16(af[mi], bf_[ni], acc[mi][ni]);
    __syncthreads();
  }
#pragma unroll
  for (int ni = 0; ni < 4; ++ni) {
    int col = n0 + wc * 64 + ni * 16 + fr;
    float bv = bias[col];
    int dir = col >> 12, grow = col & (NG - 1);
    int gg = grow >> 10, uu = grow & 1023;
    bf16* base = gxout + ((size_t)dir * 300 * 4 + gg) * 32768 + uu;
#pragma unroll
    for (int mi = 0; mi < 4; ++mi) {
#pragma unroll
      for (int j = 0; j < 4; ++j) {
        int row = m0 + wr * 64 + mi * 16 + fq * 4 + j;
        int tt = row >> 5, b = row & 31;
        base[(size_t)tt * 131072 + b * 1024] = (bf16)(acc[mi][ni][j] + bv);
      }
    }
  }
}

// ---------------- per-layer init: h buffer (par 0) + flags + election slots ----------------
__global__ __launch_bounds__(256) void k_init(const float* __restrict__ h0,
                                              bf16* __restrict__ hbuf,
                                              int* __restrict__ flags, int layer) {
  int i = blockIdx.x * 256 + threadIdx.x;  // 65536 = [2 dir][32][1024]
  hbuf[i] = (bf16)h0[(size_t)layer * 65536 + i];
  if (blockIdx.x == 0) {
    for (int j = threadIdx.x; j < 64 * FPAD; j += 256) flags[j] = 0;
    if (threadIdx.x == 0) {
      flags[ELEC_A] = -1; flags[ELEC_B] = -1;
      flags[ELEC_R0] = 0; flags[ELEC_R1] = 0; flags[ELEC_G] = 0;
    }
  }
}

// ---------------- fused persistent kernel: recurrence + next-layer GEMM ----------------
// grid = 256 blocks x 512 threads; 128KB static LDS -> 1 block/CU -> all co-resident
// (proven by r11-r18: GEMM blocks spin on flags only rec can advance).
// r19: XCD election (m09 HW_REG_XCC_ID, __hip_atomic CAS/rank). dir0 = first-claimed
// XCD's 32 blocks, dir1 = second; others = GEMM role. h exchange becomes XCD-local:
// plain-store publish (dirty in local L2, fast ack) + sc0 (GLC) DMA restage (L1-bypass,
// L2-serve). Flags stay L3 __hip_atomic (proven). y/gx/dout paths unchanged from r18.
__global__ __launch_bounds__(512, 1) void k_rec(
    const bf16* __restrict__ whh,   // [2][4096][1024] (this layer)
    const bf16* __restrict__ gxT,   // [2][300][4][32][1024] bf16, biases folded
    const float* __restrict__ h0,   // [6][32][1024]
    bf16* __restrict__ hbuf,        // [2 par][2 dir][32][1024]
    int* __restrict__ flags,        // [64*FPAD + election], init by k_init
    bf16* __restrict__ yout,        // [9600][2048] or null (layer 2)
    float* __restrict__ dout,
    int layer,
    const bf16* __restrict__ gB,    // next-layer w_ih bf16 [8192][2048] (gemm role)
    const float* __restrict__ gbias,// next-layer bias sums [8192]
    int ngemm) {
  __shared__ char smem_[131072];
  // rec role:  [0..65536) h tile | EX f32 [4][128][33] aliases | [67584..83968) GXL 2x8KB
  // gemm role: 4-slot ring, slot s at [s*32768): As 256x32 bf16 (16KB) | Bs 256x32 (16KB)
  float* EX = (float*)smem_;
  char* GXL = smem_ + 67584;
  __shared__ int role2[2];

  const int tid = threadIdx.x;

  // ---- one-time XCD election (agent-scope atomics; co-residency proven) ----
  if (tid == 0) {
    int xcd;
    asm volatile("s_getreg_b32 %0, hwreg(HW_REG_XCC_ID)" : "=s"(xcd));
    xcd &= 0xf;
    int expct = -1;
    __hip_atomic_compare_exchange_strong(&flags[ELEC_A], &expct, xcd,
        __ATOMIC_ACQ_REL, __ATOMIC_RELAXED, __HIP_MEMORY_SCOPE_AGENT);
    int A;
    while ((A = __hip_atomic_load(&flags[ELEC_A], __ATOMIC_RELAXED,
                                  __HIP_MEMORY_SCOPE_AGENT)) == -1) {}
    int dir_ = -1;
    if (xcd == A) {
      dir_ = 0;
    } else {
      expct = -1;
      __hip_atomic_compare_exchange_strong(&flags[ELEC_B], &expct, xcd,
          __ATOMIC_ACQ_REL, __ATOMIC_RELAXED, __HIP_MEMORY_SCOPE_AGENT);
      int B;
      while ((B = __hip_atomic_load(&flags[ELEC_B], __ATOMIC_RELAXED,
                                    __HIP_MEMORY_SCOPE_AGENT)) == -1) {}
      if (xcd == B) dir_ = 1;
    }
    int rk;
    if (dir_ >= 0)
      rk = __hip_atomic_fetch_add(&flags[dir_ ? ELEC_R1 : ELEC_R0], 1,
                                  __ATOMIC_RELAXED, __HIP_MEMORY_SCOPE_AGENT);
    else
      rk = __hip_atomic_fetch_add(&flags[ELEC_G], 1,
                                  __ATOMIC_RELAXED, __HIP_MEMORY_SCOPE_AGENT);
    role2[0] = dir_; role2[1] = rk;
  }
  __syncthreads();
  const int dirx = role2[0];
  const int rankx = role2[1];

  // ================= GEMM role: non-elected blocks =================
  if (dirx < 0) {
    const int gid = rankx;
    if (gid >= ngemm) return;
    const int lane = tid & 63, wid = tid >> 6;
    const int wm = wid >> 1, wn = wid & 1;     // 4m x 2n wave grid; wave tile 64x128
    const int fr = lane & 15, fq = lane >> 4;
    // staging: 512 threads sweep a [128][32] half-tile; LDS addr = base + tid*16
    // (global_load_lds HW writes wave-uniform-base + lane*16 — must match, m104/m108)
    const int srow = tid >> 2;                 // 0..127
    const int scol = (tid & 3) * 8;            // element col 0,8,16,24
    const int l16 = tid * 16;                  // lane-contiguous LDS byte offset
#pragma unroll 1
    for (int i = 0; i < 7; ++i) {
      const int lin = i * 192 + gid;           // 1216 tiles = 38 m x 32 n
      if (lin >= 1216) break;
      const int n0 = (lin & 31) << 8;          // fixed per block (192 % 32 == 0)
      const int mrank = lin >> 5;              // readiness rank: center-out m
      const int m = (mrank & 1) ? (19 + (mrank >> 1)) : (18 - (mrank >> 1));
      const int m0 = m << 8;
      int ra = 8 * m + 7; if (ra > 299) ra = 299;
      const int rb = 299 - 8 * m;
      const int thr = (ra > rb ? ra : rb) + 2; // y(band) drained & gx(band) dead
      if (tid < 64) {
        while (__hip_atomic_load(&flags[tid * FPAD], __ATOMIC_RELAXED,
                                 __HIP_MEMORY_SCOPE_AGENT) < thr)
          __builtin_amdgcn_s_sleep(200);       // ~13.6us: off rec's flag lines
      }
      __syncthreads();
      // acquire: invalidate stale local L1/L2 so cached y reads see rec's stores
      __builtin_amdgcn_fence(__ATOMIC_ACQUIRE, "agent");

      // band-37 A over-read past row 9599 lands in adjacent ws regions: safe
      const bf16* ArowL = yout + (size_t)(m0 + srow) * 2048 + scol;
      const bf16* ArowH = yout + (size_t)(m0 + 128 + srow) * 2048 + scol;
      const bf16* BrowL = gB + (size_t)(n0 + srow) * 2048 + scol;
      const bf16* BrowH = gB + (size_t)(n0 + 128 + srow) * 2048 + scol;

      auto stage = [&](int ks) {
        char* buf = smem_ + (ks & 3) * 32768;
        gload_lds16(ArowL + ks * 32, buf + l16);            // A rows   0..127
        gload_lds16(ArowH + ks * 32, buf + 8192 + l16);     // A rows 128..255
        gload_lds16(BrowL + ks * 32, buf + 16384 + l16);    // B rows   0..127
        gload_lds16(BrowH + ks * 32, buf + 24576 + l16);    // B rows 128..255
      };

      f32x4 acc[4][8] = {};
      auto compute = [&](int k) {
        const bf16* As = (const bf16*)(smem_ + (k & 3) * 32768);
        const bf16* Bs = As + 8192;
        bf16x8 af[4], bfv[8];
#pragma unroll
        for (int i2 = 0; i2 < 4; ++i2)
          af[i2] = *(const bf16x8*)(As + (wm * 64 + i2 * 16 + fr) * 32 + fq * 8);
#pragma unroll
        for (int i2 = 0; i2 < 8; ++i2)
          bfv[i2] = *(const bf16x8*)(Bs + (wn * 128 + i2 * 16 + fr) * 32 + fq * 8);
#pragma unroll
        for (int mi = 0; mi < 4; ++mi)
#pragma unroll
          for (int ni = 0; ni < 8; ++ni)
            acc[mi][ni] = mfma16(af[mi], bfv[ni], acc[mi][ni]);
      };

      // prologue: fill the 4-slot ring (16 outstanding loads/thread)
      stage(0); stage(1); stage(2); stage(3);

      // main: wait only for the oldest stage (4 loads) -> 12 may stay in flight
#pragma unroll 1
      for (int k = 0; k < 60; ++k) {
        asm volatile("s_waitcnt vmcnt(12)" ::: "memory");
        GBAR();
        __builtin_amdgcn_sched_barrier(0);
        compute(k);
        __builtin_amdgcn_sched_barrier(0);
        GBAR();
        stage(k + 4);                        // k+4 <= 63
      }
      // tail: descending waits (no new stages; outstanding shrinks by 4 per iter)
#define GTAIL(K, WAITS)                                          \
      asm volatile("s_waitcnt vmcnt(" WAITS ")" ::: "memory");   \
      GBAR();                                                    \
      __builtin_amdgcn_sched_barrier(0);                         \
      compute(K);                                                \
      __builtin_amdgcn_sched_barrier(0);                         \
      GBAR();
      GTAIL(60, "12") GTAIL(61, "8") GTAIL(62, "4") GTAIL(63, "0")
#undef GTAIL

      // epilogue -> gxT layout (same as layer-0 GEMM); guard row<9600 (band 37 half)
#pragma unroll
      for (int ni = 0; ni < 8; ++ni) {
        int col = n0 + wn * 128 + ni * 16 + fr;
        float bv = gbias[col];
        int dirv = col >> 12, grow = col & (NG - 1);
        int gg = grow >> 10, uu = grow & 1023;
        bf16* base = (bf16*)gxT + ((size_t)dirv * 1200 + gg) * 32768 + uu;
#pragma unroll
        for (int mi = 0; mi < 4; ++mi) {
#pragma unroll
          for (int j = 0; j < 4; ++j) {
            int row = m0 + wm * 64 + mi * 16 + fq * 4 + j;
            if (row < MROWS) {
              int tt = row >> 5, b = row & 31;
              base[(size_t)tt * 131072 + b * 1024] = (bf16)(acc[mi][ni][j] + bv);
            }
          }
        }
      }
    }
    return;
  }

  // ================= recurrence role: 32 blocks per elected XCD =================
  const int dir = dirx;
  const int rank = rankx;
  const int u0 = rank << 5;
  const int w = tid >> 6, lane = tid & 63;
  const int fr = lane & 15, fq = lane >> 4;
  const int kh = w >> 1, rh = w & 1;
  const int fidx = (dir * 32 + rank) * FPAD;

  // ---- weights -> registers (64 rows x K=256 per wave = 128 regs/lane), pinned ----
  f32x4 wf[32];
#pragma unroll
  for (int rg = 0; rg < 4; ++rg) {
    int rowb = rh * 64 + rg * 16 + fr;  // block gate-row 0..127 (= g*32 + u_local)
    const bf16* Wp = whh + ((size_t)dir * 4096 + (rowb >> 5) * 1024 + u0 + (rowb & 31)) * 1024
                     + kh * 256 + fq * 8;
#pragma unroll
    for (int it = 0; it < 8; ++it) wf[rg * 8 + it] = *(const f32x4*)(Wp + it * 32);
  }
#pragma unroll
  for (int i = 0; i < 32; ++i) asm volatile("" : "+v"(wf[i]));

  // ---- cell state in registers; c init = h0 (reference's cn=hn bug) ----
  const int b_pt = tid >> 4;           // batch 0..31
  const int ul_pt = (tid & 15) << 1;   // local unit 0,2,..,30
  const int ug_pt = u0 + ul_pt;
  const size_t soff = ((size_t)layer * 2 + dir) * 32768 + (size_t)b_pt * 1024 + ug_pt;
  float c0 = h0[soff], c1 = h0[soff + 1];
  float hl0 = 0.f, hl1 = 0.f;

  // gx DMA mapping: thread -> (gate, b, 16B quarter)
  const int gg = tid >> 7, sub = tid & 127;
  const size_t gx_base0 = ((size_t)dir * 1200 + gg) * 32768
                          + (size_t)(sub >> 2) * 1024 + u0 + (sub & 3) * 8;

  // h-stage source offsets (t-invariant): linear LDS dest, inverse-swizzled source
  int srcoff[8];
#pragma unroll
  for (int r = 0; r < 8; ++r) {
    int d = r * 8192 + tid * 16;
    int row = d >> 11, colb = d & 2047;
    srcoff[r] = row * 2048 + (colb ^ ((row & 7) << 4));
  }
  const int swz = (fr & 7) << 4;

  // ---- prologue: gx(0) DMA into buffer 0 ----
  {
    const int ts0 = dir ? (T_SEQ - 1) : 0;
    gload_lds16(gxT + gx_base0 + (size_t)ts0 * 131072, GXL + tid * 16);
  }

#pragma unroll 1
  for (int t = 0; t < T_SEQ; ++t) {
    const int tseq = dir ? (T_SEQ - 1 - t) : t;

    // ---- barrier: all same-dir blocks published h(t-1); padded flag lines ----
    if (tid < 32) {
      while (__hip_atomic_load(&flags[(dir * 32 + tid) * FPAD], __ATOMIC_RELAXED,
                               __HIP_MEMORY_SCOPE_AGENT) < t)
        __builtin_amdgcn_s_sleep(1);
    }
    __syncthreads();

    // ---- stage h(dir) 64KB -> LDS from THIS XCD's L2 (sc0 = GLC: L1-bypass) ----
    const char* hsrc = (const char*)hbuf + (((size_t)(t & 1) * 2 + dir) << 16);
#pragma unroll
    for (int r = 0; r < 8; ++r)
      gload_lds16_sc0(hsrc + srcoff[r], smem_ + r * 8192 + tid * 16);
    asm volatile("s_waitcnt vmcnt(0)" ::: "memory");
    __syncthreads();

    // ---- matvec: K-split-4, 64 MFMA from LDS(h) x reg(W) ----
    f32x4 acc[4][2] = {};
    const char* hb0 = smem_ + fr * 2048;
#pragma unroll
    for (int it = 0; it < 8; ++it) {
      int col = kh * 512 + it * 64 + fq * 16;
      bf16x8 ha0 = *(const bf16x8*)(hb0 + (col ^ swz));
      bf16x8 ha1 = *(const bf16x8*)(hb0 + 32768 + (col ^ swz));
#pragma unroll
      for (int rg = 0; rg < 4; ++rg) {
        bf16x8 wv = __builtin_bit_cast(bf16x8, wf[rg * 8 + it]);
        acc[rg][0] = mfma16(ha0, wv, acc[rg][0]);
        acc[rg][1] = mfma16(ha1, wv, acc[rg][1]);
      }
    }
    __syncthreads();  // all waves done reading h tile; EX aliases it

    // ---- exchange K-partials via LDS (f32, stride 33) ----
#pragma unroll
    for (int rg = 0; rg < 4; ++rg) {
      int rowb = rh * 64 + rg * 16 + fr;
      float* exr = EX + (size_t)(kh * 128 + rowb) * 33;
#pragma unroll
      for (int j = 0; j < 4; ++j) {
        exr[fq * 4 + j]      = acc[rg][0][j];
        exr[16 + fq * 4 + j] = acc[rg][1][j];
      }
    }
    __syncthreads();

    // ---- pointwise: 2 (b,u) pairs/thread; sum 4 K-partials + gx(LDS) ----
    const bf16* gxb = (const bf16*)(GXL + (t & 1) * 8192);
    float hv[2]; float cc[2] = {c0, c1};
#pragma unroll
    for (int q = 0; q < 2; ++q) {
      int ul = ul_pt + q;
      float gt[4];
#pragma unroll
      for (int g2 = 0; g2 < 4; ++g2) {
        int rowb = g2 * 32 + ul;
        float s = EX[(size_t)(0 * 128 + rowb) * 33 + b_pt]
                + EX[(size_t)(1 * 128 + rowb) * 33 + b_pt]
                + EX[(size_t)(2 * 128 + rowb) * 33 + b_pt]
                + EX[(size_t)(3 * 128 + rowb) * 33 + b_pt];
        gt[g2] = s + (float)gxb[(g2 * 32 + b_pt) * 32 + ul];
      }
      float iv = fminf(fmaxf(__builtin_fmaf(0.2f, gt[0], 0.5f), 0.f), 1.f);
      float fv = fminf(fmaxf(__builtin_fmaf(0.2f, gt[1], 0.5f), 0.f), 1.f);
      float gv = fminf(fmaxf(gt[2], -1.f), 1.f);
      float ov = fminf(fmaxf(__builtin_fmaf(0.2f, gt[3], 0.5f), 0.f), 1.f);
      float c = fv * cc[q] + iv * gv;
      cc[q] = c;
      hv[q] = ov * fminf(fmaxf(c, -1.f), 1.f);
    }
    c0 = cc[0]; c1 = cc[1]; hl0 = hv[0]; hl1 = hv[1];

    // ---- publish h: PLAIN store -> lands in this XCD's L2 (readers same-XCD) ----
    unsigned hp;
    { union { bf16 h[2]; unsigned u; } pk; pk.h[0] = (bf16)hv[0]; pk.h[1] = (bf16)hv[1]; hp = pk.u; }
    {
      unsigned* hdst = (unsigned*)((char*)hbuf + (((size_t)((t + 1) & 1) * 2 + dir) << 16))
                       + (((size_t)b_pt * 1024 + ug_pt) >> 1);
      asm volatile("global_store_dword %0, %1, off" :: "v"(hdst), "v"(hp) : "memory");
    }
    asm volatile("s_waitcnt vmcnt(0)" ::: "memory");
    __syncthreads();   // all h stores in L2 before flag release
    if (tid == 0)
      __hip_atomic_store(&flags[fidx], t + 1, __ATOMIC_RELAXED, __HIP_MEMORY_SCOPE_AGENT);

    // ---- off-path: y stores (write-through: cross-XCD gemm consumers read via L3)
    //      + gx(t+1) prefetch; both drained by NEXT step's publish vmcnt ----
    if (yout) {
      volatile unsigned* yd =
          (volatile unsigned*)((char*)yout
              + (((size_t)tseq * 32 + b_pt) * 2048 + dir * 1024 + ug_pt) * 2);
      *yd = hp;
    } else {
      float* yd = dout + ((size_t)tseq * 32 + b_pt) * 2048 + dir * 1024 + ug_pt;
      yd[0] = hv[0]; yd[1] = hv[1];
    }
    if (t + 1 < T_SEQ) {
      const int tn = dir ? (T_SEQ - 2 - t) : (t + 1);
      gload_lds16(gxT + gx_base0 + (size_t)tn * 131072,
                  GXL + ((t + 1) & 1) * 8192 + tid * 16);
    }
  }

  // ---- final (h,c) states; drain everything; release terminal flag (>= all thr) ----
  dout[OUT_Y + soff] = hl0;
  dout[OUT_Y + soff + 1] = hl1;
  dout[OUT_Y + HN_SZ + soff] = c0;
  dout[OUT_Y + HN_SZ + soff + 1] = c1;
  asm volatile("s_waitcnt vmcnt(0)" ::: "memory");
  __syncthreads();
  if (tid == 0)
    __hip_atomic_store(&flags[fidx], 302, __ATOMIC_RELAXED, __HIP_MEMORY_SCOPE_AGENT);
}

// ---------------- host launcher ----------------
extern "C" void kernel_launch(void* const* d_in, const int* in_sizes, int n_in,
                              void* d_out, int out_size, void* d_ws, size_t ws_size,
                              hipStream_t stream) {
  const float* x     = (const float*)d_in[0];
  const float* h0    = (const float*)d_in[1];
  // d_in[2] = c0: unused (reference init bug: cn = hn = h0)
  const float* w_ih0 = (const float*)d_in[3];
  const float* w_hh0 = (const float*)d_in[4];
  const float* b_ih0 = (const float*)d_in[5];
  const float* b_hh0 = (const float*)d_in[6];
  const float* w_ihL = (const float*)d_in[7];
  const float* w_hhL = (const float*)d_in[8];
  const float* b_ihL = (const float*)d_in[9];
  const float* b_hhL = (const float*)d_in[10];
  float* dout = (float*)d_out;
  char* ws = (char*)d_ws;

  // ---- workspace carve (bytes) ----
  const size_t OFF_XB   = 0;                         // bf16 [9600][320]
  const size_t OFF_WIH0 = 6144000;                   // bf16 [8192][320]
  const size_t OFF_WIHL = 11386880;                  // bf16 [2][8192][2048]
  const size_t OFF_WHH  = 78495744;                  // bf16 [6][4096][1024]
  const size_t OFF_BSUM = 128827392;                 // f32  [6][4096]
  const size_t OFF_GX   = 128925696;                 // bf16 [2][300][4][32][1024]
  const size_t OFF_Y0   = 286212096;                 // bf16 [9600][2048]
  const size_t OFF_Y1   = 325533696;                 // bf16 [9600][2048]
  const size_t OFF_HBF  = 364855296;                 // bf16 [2 par][2 dir][32][1024]
  const size_t OFF_FLG  = 365117440;                 // int  [64*FPAD + election]

  bf16*  xb    = (bf16*)(ws + OFF_XB);
  bf16*  wih0b = (bf16*)(ws + OFF_WIH0);
  bf16*  wihLb = (bf16*)(ws + OFF_WIHL);
  bf16*  whhb  = (bf16*)(ws + OFF_WHH);
  float* bsum  = (float*)(ws + OFF_BSUM);
  bf16*  gx    = (bf16*)(ws + OFF_GX);
  bf16*  y0    = (bf16*)(ws + OFF_Y0);
  bf16*  y1    = (bf16*)(ws + OFF_Y1);
  bf16*  hbuf  = (bf16*)(ws + OFF_HBF);
  int*   flags = (int*)(ws + OFF_FLG);

  auto cvt = [&](const float* s, bf16* d, size_t n) {
    int n8 = (int)(n / 8);
    int grid = (n8 + 255) / 256; if (grid > 2048) grid = 2048;
    k_cvt<<<grid, 256, 0, stream>>>(s, d, n8);
  };

  cvt(x,     xb,    (size_t)MROWS * DIN);
  cvt(w_ih0, wih0b, (size_t)2 * NG * DIN);
  cvt(w_ihL, wihLb, (size_t)2 * 2 * NG * 2048);
  cvt(w_hh0, whhb,  (size_t)2 * NG * NH);
  cvt(w_hhL, whhb + (size_t)2 * NG * NH, (size_t)4 * NG * NH);
  k_bsum<<<96, 256, 0, stream>>>(b_ih0, b_hh0, b_ihL, b_hhL, bsum);

  // layer-0 gx GEMM (input x available immediately)
  k_gemm_gx<<<dim3(64, 75), 256, 0, stream>>>(xb, wih0b, bsum, gx, DIN);

  for (int l = 0; l < 3; ++l) {
    k_init<<<256, 256, 0, stream>>>(h0, hbuf, flags, l);

    const bf16* whh_l = whhb + (size_t)l * 2 * NG * NH;
    bf16* yout = (l == 0) ? y0 : (l == 1 ? y1 : nullptr);
    const int ngemm = (l < 2) ? 192 : 0;
    const bf16* gB = wihLb + (size_t)l * 2 * NG * 2048;   // next layer's w_ih
    const float* gbias = bsum + (size_t)(l + 1) * 2 * NG;
    k_rec<<<256, 512, 0, stream>>>(whh_l, gx, h0, hbuf, flags, yout, dout, l,
                                   gB, gbias, ngemm);
  }
  (void)in_sizes; (void)n_in; (void)out_size; (void)ws_size;
}

// Round 20
// 3826.789 us; speedup vs baseline: 1.3365x; 1.0176x over previous
//
#include <hip/hip_runtime.h>

typedef __bf16 bf16;
typedef __attribute__((ext_vector_type(8))) __bf16 bf16x8;
typedef __attribute__((ext_vector_type(4))) float f32x4;

#define GLOBAL_AS __attribute__((address_space(1)))
#define LDS_AS __attribute__((address_space(3)))

__device__ __forceinline__ void gload_lds16(const void* g, void* l) {
  __builtin_amdgcn_global_load_lds((const GLOBAL_AS void*)g, (LDS_AS void*)l, 16, 0, 0);
}
// sc0-only (GLC): L1-bypass, served from local L2 — for same-XCD-fresh h reads
__device__ __forceinline__ void gload_lds16_sc0(const void* g, void* l) {
  __builtin_amdgcn_global_load_lds((const GLOBAL_AS void*)g, (LDS_AS void*)l, 16, 0, 0x1);
}

__device__ __forceinline__ f32x4 mfma16(bf16x8 a, bf16x8 b, f32x4 c) {
  return __builtin_amdgcn_mfma_f32_16x16x32_bf16(a, b, c, 0, 0, 0);
}

// hardware barrier + compiler memory fence
#define GBAR() asm volatile("s_barrier" ::: "memory")

// ---------------- constants ----------------
#define T_SEQ 300
#define NBATCH 32
#define DIN 320
#define NH 1024
#define NG 4096              // 4*NH
#define MROWS 9600           // T_SEQ*NBATCH
#define OUT_Y 19660800       // T*B*2H
#define HN_SZ 196608         // 6*32*1024
#define FPAD 32              // flag padding: one 128B line per flag
#define ELEC_A (64 * FPAD)       // election slot: dir0 XCD
#define ELEC_B (64 * FPAD + 8)   // election slot: dir1 XCD
#define ELEC_R0 (64 * FPAD + 16) // rank counter dir0
#define ELEC_R1 (64 * FPAD + 24) // rank counter dir1
#define ELEC_G (64 * FPAD + 32)  // gemm block-id counter (unused for tiles now)
#define ELEC_T (64 * FPAD + 40)  // dynamic tile-claim counter
#define NTILES 1216              // 38 m-bands x 32 n-panels

// ---------------- f32 -> bf16 convert ----------------
__global__ __launch_bounds__(256) void k_cvt(const float* __restrict__ src,
                                             bf16* __restrict__ dst, int n8) {
  int stride = gridDim.x * blockDim.x;
  for (int i = blockIdx.x * blockDim.x + threadIdx.x; i < n8; i += stride) {
    const float* s = src + (size_t)i * 8;
    f32x4 a = *(const f32x4*)s;
    f32x4 b = *(const f32x4*)(s + 4);
    bf16x8 o;
#pragma unroll
    for (int j = 0; j < 4; ++j) { o[j] = (bf16)a[j]; o[j + 4] = (bf16)b[j]; }
    *(bf16x8*)(dst + (size_t)i * 8) = o;
  }
}

// ---------------- bias sums: bsum[l][dir][4096] = b_ih + b_hh ----------------
__global__ __launch_bounds__(256) void k_bsum(const float* __restrict__ bih0,
                                              const float* __restrict__ bhh0,
                                              const float* __restrict__ bihL,
                                              const float* __restrict__ bhhL,
                                              float* __restrict__ bsum) {
  int i = blockIdx.x * 256 + threadIdx.x;  // n = 6*4096 = 24576
  if (i < 2 * NG) bsum[i] = bih0[i] + bhh0[i];
  else            bsum[i] = bihL[i - 2 * NG] + bhhL[i - 2 * NG];
}

// ---------------- GX GEMM (layer 0 only): gxT[dir][t][g][b][u] ----------------
__global__ __launch_bounds__(256) void k_gemm_gx(const bf16* __restrict__ A,
                                                 const bf16* __restrict__ Bw,
                                                 const float* __restrict__ bias,
                                                 bf16* __restrict__ gxout, int K) {
  __shared__ bf16 As[128 * 32];
  __shared__ bf16 Bs[128 * 32];
  const int t = threadIdx.x;
  const int m0 = blockIdx.y * 128, n0 = blockIdx.x * 128;
  const int lane = t & 63, wid = t >> 6;
  const int wr = wid >> 1, wc = wid & 1;
  const int fr = lane & 15, fq = lane >> 4;
  f32x4 acc[4][4] = {};
  for (int k0 = 0; k0 < K; k0 += 32) {
#pragma unroll
    for (int r = 0; r < 2; ++r) {
      int idx = r * 256 + t;
      int row = idx >> 2, kk = (idx & 3) * 8;
      gload_lds16(A + (size_t)(m0 + row) * K + k0 + kk, As + (size_t)idx * 8);
      gload_lds16(Bw + (size_t)(n0 + row) * K + k0 + kk, Bs + (size_t)idx * 8);
    }
    asm volatile("s_waitcnt vmcnt(0)" ::: "memory");
    __syncthreads();
    bf16x8 af[4], bf_[4];
#pragma unroll
    for (int i2 = 0; i2 < 4; ++i2) {
      af[i2]  = *(const bf16x8*)(As + (wr * 64 + i2 * 16 + fr) * 32 + fq * 8);
      bf_[i2] = *(const bf16x8*)(Bs + (wc * 64 + i2 * 16 + fr) * 32 + fq * 8);
    }
#pragma unroll
    for (int mi = 0; mi < 4; ++mi)
#pragma unroll
      for (int ni = 0; ni < 4; ++ni)
        acc[mi][ni] = mfma16(af[mi], bf_[ni], acc[mi][ni]);
    __syncthreads();
  }
#pragma unroll
  for (int ni = 0; ni < 4; ++ni) {
    int col = n0 + wc * 64 + ni * 16 + fr;
    float bv = bias[col];
    int dir = col >> 12, grow = col & (NG - 1);
    int gg = grow >> 10, uu = grow & 1023;
    bf16* base = gxout + ((size_t)dir * 300 * 4 + gg) * 32768 + uu;
#pragma unroll
    for (int mi = 0; mi < 4; ++mi) {
#pragma unroll
      for (int j = 0; j < 4; ++j) {
        int row = m0 + wr * 64 + mi * 16 + fq * 4 + j;
        int tt = row >> 5, b = row & 31;
        base[(size_t)tt * 131072 + b * 1024] = (bf16)(acc[mi][ni][j] + bv);
      }
    }
  }
}

// ---------------- per-layer init: h buffer (par 0) + flags + election slots ----------------
__global__ __launch_bounds__(256) void k_init(const float* __restrict__ h0,
                                              bf16* __restrict__ hbuf,
                                              int* __restrict__ flags, int layer) {
  int i = blockIdx.x * 256 + threadIdx.x;  // 65536 = [2 dir][32][1024]
  hbuf[i] = (bf16)h0[(size_t)layer * 65536 + i];
  if (blockIdx.x == 0) {
    for (int j = threadIdx.x; j < 64 * FPAD; j += 256) flags[j] = 0;
    if (threadIdx.x == 0) {
      flags[ELEC_A] = -1; flags[ELEC_B] = -1;
      flags[ELEC_R0] = 0; flags[ELEC_R1] = 0; flags[ELEC_G] = 0;
      flags[ELEC_T] = 0;
    }
  }
}

// ---------------- GEMM worker: claim tiles dynamically in readiness order ----------------
// 256x256 tile, BK=32, 4-slot counted-vmcnt ring. Staging LDS addr = base + tid*16
// (global_load_lds HW writes wave-uniform-base + lane*16 — must match, m104/m108).
__device__ __forceinline__ void gemm_worker(
    char* smem_, int* claimo, int tid, int* flags,
    const bf16* __restrict__ yout, const bf16* __restrict__ gB,
    const float* __restrict__ gbias, bf16* __restrict__ gxout) {
  const int lane = tid & 63, wid = tid >> 6;
  const int wm = wid >> 1, wn = wid & 1;       // 4m x 2n wave grid; wave tile 64x128
  const int fr = lane & 15, fq = lane >> 4;
  const int srow = tid >> 2;                   // 0..127
  const int scol = (tid & 3) * 8;              // element col 0,8,16,24
  const int l16 = tid * 16;                    // lane-contiguous LDS byte offset
#pragma unroll 1
  for (;;) {
    if (tid == 0)
      *claimo = __hip_atomic_fetch_add(&flags[ELEC_T], 1,
                                       __ATOMIC_RELAXED, __HIP_MEMORY_SCOPE_AGENT);
    __syncthreads();
    const int lin = *claimo;                   // uniform across block
    if (lin >= NTILES) return;
    const int n0 = (lin & 31) << 8;
    const int mrank = lin >> 5;                // readiness rank: center-out m
    const int m = (mrank & 1) ? (19 + (mrank >> 1)) : (18 - (mrank >> 1));
    const int m0 = m << 8;
    int ra = 8 * m + 7; if (ra > 299) ra = 299;
    const int rb = 299 - 8 * m;
    const int thr = (ra > rb ? ra : rb) + 2;   // y(band) drained & gx(band) dead
    if (tid < 64) {
      while (__hip_atomic_load(&flags[tid * FPAD], __ATOMIC_RELAXED,
                               __HIP_MEMORY_SCOPE_AGENT) < thr)
        __builtin_amdgcn_s_sleep(200);         // ~13.6us: off rec's flag lines
    }
    __syncthreads();
    // acquire: invalidate stale local L1/L2 so cached y reads see rec's stores
    __builtin_amdgcn_fence(__ATOMIC_ACQUIRE, "agent");

    // band-37 A over-read past row 9599 lands in adjacent ws regions: safe
    const bf16* ArowL = yout + (size_t)(m0 + srow) * 2048 + scol;
    const bf16* ArowH = yout + (size_t)(m0 + 128 + srow) * 2048 + scol;
    const bf16* BrowL = gB + (size_t)(n0 + srow) * 2048 + scol;
    const bf16* BrowH = gB + (size_t)(n0 + 128 + srow) * 2048 + scol;

    auto stage = [&](int ks) {
      char* buf = smem_ + (ks & 3) * 32768;
      gload_lds16(ArowL + ks * 32, buf + l16);            // A rows   0..127
      gload_lds16(ArowH + ks * 32, buf + 8192 + l16);     // A rows 128..255
      gload_lds16(BrowL + ks * 32, buf + 16384 + l16);    // B rows   0..127
      gload_lds16(BrowH + ks * 32, buf + 24576 + l16);    // B rows 128..255
    };

    f32x4 acc[4][8] = {};
    auto compute = [&](int k) {
      const bf16* As = (const bf16*)(smem_ + (k & 3) * 32768);
      const bf16* Bs = As + 8192;
      bf16x8 af[4], bfv[8];
#pragma unroll
      for (int i2 = 0; i2 < 4; ++i2)
        af[i2] = *(const bf16x8*)(As + (wm * 64 + i2 * 16 + fr) * 32 + fq * 8);
#pragma unroll
      for (int i2 = 0; i2 < 8; ++i2)
        bfv[i2] = *(const bf16x8*)(Bs + (wn * 128 + i2 * 16 + fr) * 32 + fq * 8);
#pragma unroll
      for (int mi = 0; mi < 4; ++mi)
#pragma unroll
        for (int ni = 0; ni < 8; ++ni)
          acc[mi][ni] = mfma16(af[mi], bfv[ni], acc[mi][ni]);
    };

    // prologue: fill the 4-slot ring (16 outstanding loads/thread)
    stage(0); stage(1); stage(2); stage(3);

    // main: wait only for the oldest stage (4 loads) -> 12 may stay in flight
#pragma unroll 1
    for (int k = 0; k < 60; ++k) {
      asm volatile("s_waitcnt vmcnt(12)" ::: "memory");
      GBAR();
      __builtin_amdgcn_sched_barrier(0);
      compute(k);
      __builtin_amdgcn_sched_barrier(0);
      GBAR();
      stage(k + 4);                        // k+4 <= 63
    }
    // tail: descending waits (no new stages; outstanding shrinks by 4 per iter)
#define GTAIL(K, WAITS)                                          \
    asm volatile("s_waitcnt vmcnt(" WAITS ")" ::: "memory");     \
    GBAR();                                                      \
    __builtin_amdgcn_sched_barrier(0);                           \
    compute(K);                                                  \
    __builtin_amdgcn_sched_barrier(0);                           \
    GBAR();
    GTAIL(60, "12") GTAIL(61, "8") GTAIL(62, "4") GTAIL(63, "0")
#undef GTAIL

    // epilogue -> gxT layout (same as layer-0 GEMM); guard row<9600 (band 37 half)
#pragma unroll
    for (int ni = 0; ni < 8; ++ni) {
      int col = n0 + wn * 128 + ni * 16 + fr;
      float bv = gbias[col];
      int dirv = col >> 12, grow = col & (NG - 1);
      int gg = grow >> 10, uu = grow & 1023;
      bf16* base = gxout + ((size_t)dirv * 1200 + gg) * 32768 + uu;
#pragma unroll
      for (int mi = 0; mi < 4; ++mi) {
#pragma unroll
        for (int j = 0; j < 4; ++j) {
          int row = m0 + wm * 64 + mi * 16 + fq * 4 + j;
          if (row < MROWS) {
            int tt = row >> 5, b = row & 31;
            base[(size_t)tt * 131072 + b * 1024] = (bf16)(acc[mi][ni][j] + bv);
          }
        }
      }
    }
  }
}

// ---------------- fused persistent kernel: recurrence + next-layer GEMM ----------------
// grid = 256 blocks x 512 threads; 128KB static LDS -> 1 block/CU -> all co-resident.
// XCD election (r19, proven): dir0/dir1 = first two claimed XCDs' 32 rec blocks each;
// others = GEMM workers. r20: dynamic tile claiming (readiness-ordered counter) and
// rec blocks JOIN the GEMM worker pool after their terminal flag -> tail on 256 CUs.
__global__ __launch_bounds__(512, 1) void k_rec(
    const bf16* __restrict__ whh,   // [2][4096][1024] (this layer)
    const bf16* __restrict__ gxT,   // [2][300][4][32][1024] bf16, biases folded
    const float* __restrict__ h0,   // [6][32][1024]
    bf16* __restrict__ hbuf,        // [2 par][2 dir][32][1024]
    int* __restrict__ flags,        // [64*FPAD + election], init by k_init
    bf16* __restrict__ yout,        // [9600][2048] or null (layer 2)
    float* __restrict__ dout,
    int layer,
    const bf16* __restrict__ gB,    // next-layer w_ih bf16 [8192][2048] (gemm role)
    const float* __restrict__ gbias,// next-layer bias sums [8192]
    int ngemm) {
  __shared__ char smem_[131072];
  // rec role:  [0..65536) h tile | EX f32 [4][128][33] aliases | [67584..83968) GXL 2x8KB
  // gemm role: 4-slot ring, slot s at [s*32768): As 256x32 bf16 (16KB) | Bs 256x32 (16KB)
  float* EX = (float*)smem_;
  char* GXL = smem_ + 67584;
  __shared__ int role2[2];
  __shared__ int claimo;

  const int tid = threadIdx.x;

  // ---- one-time XCD election (agent-scope atomics; co-residency proven) ----
  if (tid == 0) {
    int xcd;
    asm volatile("s_getreg_b32 %0, hwreg(HW_REG_XCC_ID)" : "=s"(xcd));
    xcd &= 0xf;
    int expct = -1;
    __hip_atomic_compare_exchange_strong(&flags[ELEC_A], &expct, xcd,
        __ATOMIC_ACQ_REL, __ATOMIC_RELAXED, __HIP_MEMORY_SCOPE_AGENT);
    int A;
    while ((A = __hip_atomic_load(&flags[ELEC_A], __ATOMIC_RELAXED,
                                  __HIP_MEMORY_SCOPE_AGENT)) == -1) {}
    int dir_ = -1;
    if (xcd == A) {
      dir_ = 0;
    } else {
      expct = -1;
      __hip_atomic_compare_exchange_strong(&flags[ELEC_B], &expct, xcd,
          __ATOMIC_ACQ_REL, __ATOMIC_RELAXED, __HIP_MEMORY_SCOPE_AGENT);
      int B;
      while ((B = __hip_atomic_load(&flags[ELEC_B], __ATOMIC_RELAXED,
                                    __HIP_MEMORY_SCOPE_AGENT)) == -1) {}
      if (xcd == B) dir_ = 1;
    }
    int rk = 0;
    if (dir_ >= 0)
      rk = __hip_atomic_fetch_add(&flags[dir_ ? ELEC_R1 : ELEC_R0], 1,
                                  __ATOMIC_RELAXED, __HIP_MEMORY_SCOPE_AGENT);
    role2[0] = dir_; role2[1] = rk;
  }
  __syncthreads();
  const int dirx = role2[0];
  const int rankx = role2[1];

  // ================= GEMM role: non-elected blocks =================
  if (dirx < 0) {
    if (ngemm > 0)
      gemm_worker(smem_, &claimo, tid, flags, yout, gB, gbias, (bf16*)gxT);
    return;
  }

  // ================= recurrence role: 32 blocks per elected XCD =================
  const int dir = dirx;
  const int rank = rankx;
  const int u0 = rank << 5;
  const int w = tid >> 6, lane = tid & 63;
  const int fr = lane & 15, fq = lane >> 4;
  const int kh = w >> 1, rh = w & 1;
  const int fidx = (dir * 32 + rank) * FPAD;

  // ---- weights -> registers (64 rows x K=256 per wave = 128 regs/lane), pinned ----
  f32x4 wf[32];
#pragma unroll
  for (int rg = 0; rg < 4; ++rg) {
    int rowb = rh * 64 + rg * 16 + fr;  // block gate-row 0..127 (= g*32 + u_local)
    const bf16* Wp = whh + ((size_t)dir * 4096 + (rowb >> 5) * 1024 + u0 + (rowb & 31)) * 1024
                     + kh * 256 + fq * 8;
#pragma unroll
    for (int it = 0; it < 8; ++it) wf[rg * 8 + it] = *(const f32x4*)(Wp + it * 32);
  }
#pragma unroll
  for (int i = 0; i < 32; ++i) asm volatile("" : "+v"(wf[i]));

  // ---- cell state in registers; c init = h0 (reference's cn=hn bug) ----
  const int b_pt = tid >> 4;           // batch 0..31
  const int ul_pt = (tid & 15) << 1;   // local unit 0,2,..,30
  const int ug_pt = u0 + ul_pt;
  const size_t soff = ((size_t)layer * 2 + dir) * 32768 + (size_t)b_pt * 1024 + ug_pt;
  float c0 = h0[soff], c1 = h0[soff + 1];
  float hl0 = 0.f, hl1 = 0.f;

  // gx DMA mapping: thread -> (gate, b, 16B quarter)
  const int gg = tid >> 7, sub = tid & 127;
  const size_t gx_base0 = ((size_t)dir * 1200 + gg) * 32768
                          + (size_t)(sub >> 2) * 1024 + u0 + (sub & 3) * 8;

  // h-stage source offsets (t-invariant): linear LDS dest, inverse-swizzled source
  int srcoff[8];
#pragma unroll
  for (int r = 0; r < 8; ++r) {
    int d = r * 8192 + tid * 16;
    int row = d >> 11, colb = d & 2047;
    srcoff[r] = row * 2048 + (colb ^ ((row & 7) << 4));
  }
  const int swz = (fr & 7) << 4;

  // ---- prologue: gx(0) DMA into buffer 0 ----
  {
    const int ts0 = dir ? (T_SEQ - 1) : 0;
    gload_lds16(gxT + gx_base0 + (size_t)ts0 * 131072, GXL + tid * 16);
  }

#pragma unroll 1
  for (int t = 0; t < T_SEQ; ++t) {
    const int tseq = dir ? (T_SEQ - 1 - t) : t;

    // ---- barrier: all same-dir blocks published h(t-1); padded flag lines ----
    if (tid < 32) {
      while (__hip_atomic_load(&flags[(dir * 32 + tid) * FPAD], __ATOMIC_RELAXED,
                               __HIP_MEMORY_SCOPE_AGENT) < t)
        __builtin_amdgcn_s_sleep(1);
    }
    __syncthreads();

    // ---- stage h(dir) 64KB -> LDS from THIS XCD's L2 (sc0 = GLC: L1-bypass) ----
    const char* hsrc = (const char*)hbuf + (((size_t)(t & 1) * 2 + dir) << 16);
#pragma unroll
    for (int r = 0; r < 8; ++r)
      gload_lds16_sc0(hsrc + srcoff[r], smem_ + r * 8192 + tid * 16);
    asm volatile("s_waitcnt vmcnt(0)" ::: "memory");
    __syncthreads();

    // ---- matvec: K-split-4, 64 MFMA from LDS(h) x reg(W) ----
    f32x4 acc[4][2] = {};
    const char* hb0 = smem_ + fr * 2048;
#pragma unroll
    for (int it = 0; it < 8; ++it) {
      int col = kh * 512 + it * 64 + fq * 16;
      bf16x8 ha0 = *(const bf16x8*)(hb0 + (col ^ swz));
      bf16x8 ha1 = *(const bf16x8*)(hb0 + 32768 + (col ^ swz));
#pragma unroll
      for (int rg = 0; rg < 4; ++rg) {
        bf16x8 wv = __builtin_bit_cast(bf16x8, wf[rg * 8 + it]);
        acc[rg][0] = mfma16(ha0, wv, acc[rg][0]);
        acc[rg][1] = mfma16(ha1, wv, acc[rg][1]);
      }
    }
    __syncthreads();  // all waves done reading h tile; EX aliases it

    // ---- exchange K-partials via LDS (f32, stride 33) ----
#pragma unroll
    for (int rg = 0; rg < 4; ++rg) {
      int rowb = rh * 64 + rg * 16 + fr;
      float* exr = EX + (size_t)(kh * 128 + rowb) * 33;
#pragma unroll
      for (int j = 0; j < 4; ++j) {
        exr[fq * 4 + j]      = acc[rg][0][j];
        exr[16 + fq * 4 + j] = acc[rg][1][j];
      }
    }
    __syncthreads();

    // ---- pointwise: 2 (b,u) pairs/thread; sum 4 K-partials + gx(LDS) ----
    const bf16* gxb = (const bf16*)(GXL + (t & 1) * 8192);
    float hv[2]; float cc[2] = {c0, c1};
#pragma unroll
    for (int q = 0; q < 2; ++q) {
      int ul = ul_pt + q;
      float gt[4];
#pragma unroll
      for (int g2 = 0; g2 < 4; ++g2) {
        int rowb = g2 * 32 + ul;
        float s = EX[(size_t)(0 * 128 + rowb) * 33 + b_pt]
                + EX[(size_t)(1 * 128 + rowb) * 33 + b_pt]
                + EX[(size_t)(2 * 128 + rowb) * 33 + b_pt]
                + EX[(size_t)(3 * 128 + rowb) * 33 + b_pt];
        gt[g2] = s + (float)gxb[(g2 * 32 + b_pt) * 32 + ul];
      }
      float iv = fminf(fmaxf(__builtin_fmaf(0.2f, gt[0], 0.5f), 0.f), 1.f);
      float fv = fminf(fmaxf(__builtin_fmaf(0.2f, gt[1], 0.5f), 0.f), 1.f);
      float gv = fminf(fmaxf(gt[2], -1.f), 1.f);
      float ov = fminf(fmaxf(__builtin_fmaf(0.2f, gt[3], 0.5f), 0.f), 1.f);
      float c = fv * cc[q] + iv * gv;
      cc[q] = c;
      hv[q] = ov * fminf(fmaxf(c, -1.f), 1.f);
    }
    c0 = cc[0]; c1 = cc[1]; hl0 = hv[0]; hl1 = hv[1];

    // ---- publish h: PLAIN store -> lands in this XCD's L2 (readers same-XCD) ----
    unsigned hp;
    { union { bf16 h[2]; unsigned u; } pk; pk.h[0] = (bf16)hv[0]; pk.h[1] = (bf16)hv[1]; hp = pk.u; }
    {
      unsigned* hdst = (unsigned*)((char*)hbuf + (((size_t)((t + 1) & 1) * 2 + dir) << 16))
                       + (((size_t)b_pt * 1024 + ug_pt) >> 1);
      asm volatile("global_store_dword %0, %1, off" :: "v"(hdst), "v"(hp) : "memory");
    }
    asm volatile("s_waitcnt vmcnt(0)" ::: "memory");
    __syncthreads();   // all h stores in L2 before flag release
    if (tid == 0)
      __hip_atomic_store(&flags[fidx], t + 1, __ATOMIC_RELAXED, __HIP_MEMORY_SCOPE_AGENT);

    // ---- off-path: y stores (write-through: cross-XCD gemm consumers read via L3)
    //      + gx(t+1) prefetch; both drained by NEXT step's publish vmcnt ----
    if (yout) {
      volatile unsigned* yd =
          (volatile unsigned*)((char*)yout
              + (((size_t)tseq * 32 + b_pt) * 2048 + dir * 1024 + ug_pt) * 2);
      *yd = hp;
    } else {
      float* yd = dout + ((size_t)tseq * 32 + b_pt) * 2048 + dir * 1024 + ug_pt;
      yd[0] = hv[0]; yd[1] = hv[1];
    }
    if (t + 1 < T_SEQ) {
      const int tn = dir ? (T_SEQ - 2 - t) : (t + 1);
      gload_lds16(gxT + gx_base0 + (size_t)tn * 131072,
                  GXL + ((t + 1) & 1) * 8192 + tid * 16);
    }
  }

  // ---- final (h,c) states; drain everything; release terminal flag (>= all thr) ----
  dout[OUT_Y + soff] = hl0;
  dout[OUT_Y + soff + 1] = hl1;
  dout[OUT_Y + HN_SZ + soff] = c0;
  dout[OUT_Y + HN_SZ + soff + 1] = c1;
  asm volatile("s_waitcnt vmcnt(0)" ::: "memory");
  __syncthreads();
  if (tid == 0)
    __hip_atomic_store(&flags[fidx], 302, __ATOMIC_RELAXED, __HIP_MEMORY_SCOPE_AGENT);

  // ---- join the GEMM tail: help finish remaining next-layer gx tiles ----
  if (ngemm > 0)
    gemm_worker(smem_, &claimo, tid, flags, yout, gB, gbias, (bf16*)gxT);
}

// ---------------- host launcher ----------------
extern "C" void kernel_launch(void* const* d_in, const int* in_sizes, int n_in,
                              void* d_out, int out_size, void* d_ws, size_t ws_size,
                              hipStream_t stream) {
  const float* x     = (const float*)d_in[0];
  const float* h0    = (const float*)d_in[1];
  // d_in[2] = c0: unused (reference init bug: cn = hn = h0)
  const float* w_ih0 = (const float*)d_in[3];
  const float* w_hh0 = (const float*)d_in[4];
  const float* b_ih0 = (const float*)d_in[5];
  const float* b_hh0 = (const float*)d_in[6];
  const float* w_ihL = (const float*)d_in[7];
  const float* w_hhL = (const float*)d_in[8];
  const float* b_ihL = (const float*)d_in[9];
  const float* b_hhL = (const float*)d_in[10];
  float* dout = (float*)d_out;
  char* ws = (char*)d_ws;

  // ---- workspace carve (bytes) ----
  const size_t OFF_XB   = 0;                         // bf16 [9600][320]
  const size_t OFF_WIH0 = 6144000;                   // bf16 [8192][320]
  const size_t OFF_WIHL = 11386880;                  // bf16 [2][8192][2048]
  const size_t OFF_WHH  = 78495744;                  // bf16 [6][4096][1024]
  const size_t OFF_BSUM = 128827392;                 // f32  [6][4096]
  const size_t OFF_GX   = 128925696;                 // bf16 [2][300][4][32][1024]
  const size_t OFF_Y0   = 286212096;                 // bf16 [9600][2048]
  const size_t OFF_Y1   = 325533696;                 // bf16 [9600][2048]
  const size_t OFF_HBF  = 364855296;                 // bf16 [2 par][2 dir][32][1024]
  const size_t OFF_FLG  = 365117440;                 // int  [64*FPAD + election]

  bf16*  xb    = (bf16*)(ws + OFF_XB);
  bf16*  wih0b = (bf16*)(ws + OFF_WIH0);
  bf16*  wihLb = (bf16*)(ws + OFF_WIHL);
  bf16*  whhb  = (bf16*)(ws + OFF_WHH);
  float* bsum  = (float*)(ws + OFF_BSUM);
  bf16*  gx    = (bf16*)(ws + OFF_GX);
  bf16*  y0    = (bf16*)(ws + OFF_Y0);
  bf16*  y1    = (bf16*)(ws + OFF_Y1);
  bf16*  hbuf  = (bf16*)(ws + OFF_HBF);
  int*   flags = (int*)(ws + OFF_FLG);

  auto cvt = [&](const float* s, bf16* d, size_t n) {
    int n8 = (int)(n / 8);
    int grid = (n8 + 255) / 256; if (grid > 2048) grid = 2048;
    k_cvt<<<grid, 256, 0, stream>>>(s, d, n8);
  };

  cvt(x,     xb,    (size_t)MROWS * DIN);
  cvt(w_ih0, wih0b, (size_t)2 * NG * DIN);
  cvt(w_ihL, wihLb, (size_t)2 * 2 * NG * 2048);
  cvt(w_hh0, whhb,  (size_t)2 * NG * NH);
  cvt(w_hhL, whhb + (size_t)2 * NG * NH, (size_t)4 * NG * NH);
  k_bsum<<<96, 256, 0, stream>>>(b_ih0, b_hh0, b_ihL, b_hhL, bsum);

  // layer-0 gx GEMM (input x available immediately)
  k_gemm_gx<<<dim3(64, 75), 256, 0, stream>>>(xb, wih0b, bsum, gx, DIN);

  for (int l = 0; l < 3; ++l) {
    k_init<<<256, 256, 0, stream>>>(h0, hbuf, flags, l);

    const bf16* whh_l = whhb + (size_t)l * 2 * NG * NH;
    bf16* yout = (l == 0) ? y0 : (l == 1 ? y1 : nullptr);
    const int ngemm = (l < 2) ? 192 : 0;
    const bf16* gB = wihLb + (size_t)l * 2 * NG * 2048;   // next layer's w_ih
    const float* gbias = bsum + (size_t)(l + 1) * 2 * NG;
    k_rec<<<256, 512, 0, stream>>>(whh_l, gx, h0, hbuf, flags, yout, dout, l,
                                   gB, gbias, ngemm);
  }
  (void)in_sizes; (void)n_in; (void)out_size; (void)ws_size;
}